// Round 2
// baseline (2356.842 us; speedup 1.0000x reference)
//
#include <hip/hip_runtime.h>
#include <hip/hip_cooperative_groups.h>
#include <math.h>

namespace cg = cooperative_groups;

// ---------------------------------------------------------------------------
// AttentionalSpikingSSMLayer  (B=8, T=16, S=256, D=512, DS=64, H=4, dh=16)
// All compute fp32 (no fp32 MFMA on CDNA4; Heaviside spikes need fp32 margin).
// R1: LIF-O ballot-gather -> dense LDS GEMM (1714 -> 1258 us).
// R2: kv_gemm vectorized LDS; combine gathers -> dense b128 dots.
// R3: NSPLIT 32->16; expf -> exp2f; LIF-O b128 LDS reads. (1143 us measured)
// R4: ONE persistent cooperative kernel for init+kv+attp0+16-step loop.
//     33 serial dispatches (launch+drain ~10us each) -> grid.sync (~1-2us).
//     Thresholds carried incrementally in registers (bit-identical chain).
//     Fallback to R3 multi-kernel path if cooperative launch unavailable.
// ---------------------------------------------------------------------------

#define NTOK   2048          // B*S
#define TSTEPS 16
#define NSPLIT 16            // key splits for flash partials (128 keys each)

#define MEMDECAY ((float)0.6065306597126334)
#define SCALE    0.25f       // 1/sqrt(dh)
#define LOG2E    1.4426950408889634f

// workspace layout (float offsets)
#define OFF_KV   ((size_t)0)                      // 16*2048*128
#define OFF_PACC ((size_t)4194304)
#define OFF_OV   ((size_t)8388608)                // 2048*512
#define OFF_H    ((size_t)9437184)                // 2048*64
#define OFF_SV   ((size_t)9568256)
#define OFF_Q    ((size_t)9699328)
#define OFF_PM   ((size_t)9830400)
#define OFF_PL   ((size_t)10092544)
#define OFF_CT   ((size_t)10354688)               // 64*512 (C transposed)
#define OFF_CNT  ((size_t)10387456)               // 32 ints: [0..15]=s, [16..31]=o
#define OFF_WT   ((size_t)10387488)               // 512*128 (Wkv transposed)

#define SMEM_FLOATS 13824                         // 55,296 B: max phase (combine)
#define INIT_TOTAL  557088

// ---------------------------------------------------------------------------
// phase bodies (shared by mega kernel and fallback wrappers)
// ---------------------------------------------------------------------------
__device__ __forceinline__ void init_body(int gtid, int gstride,
                                          const float* __restrict__ bq,
                                          const float* __restrict__ C,
                                          const float* __restrict__ Wkv,
                                          float* __restrict__ ws) {
  for (int i = gtid; i < INIT_TOTAL; i += gstride) {
    int j = i;
    if (j < 327680) {                     // zero ov+h+sv (float4)
      float4 z = {0.f, 0.f, 0.f, 0.f};
      ((float4*)(ws + OFF_OV))[j] = z;
      continue;
    }
    j -= 327680;
    if (j < 131072) { ws[OFF_Q + j] = bq[j & 63]; continue; }
    j -= 131072;
    if (j < 32768) {                      // C_t[k][c] = C[c][k]
      int k = j >> 9, c = j & 511;
      ws[OFF_CT + j] = C[c * 64 + k];
      continue;
    }
    j -= 32768;
    if (j < 65536) {                      // Wkv_t[k][o] = Wkv[o][k]
      int k = j >> 7, o = j & 127;
      ws[OFF_WT + j] = Wkv[o * 512 + k];
      continue;
    }
    j -= 65536;
    ((int*)(ws + OFF_CNT))[j] = 0;        // j < 32
  }
}

// KV projection: kv[t][n][o] = sum_d x[row][d]*Wkv[o][d] + bkv[o]
// vb in [0,512): 64-row tile. smem: xs 64*68 | wt 64*136.
__device__ __forceinline__ void kv_body(int vb, int tid,
                                        const float* __restrict__ x,
                                        const float* __restrict__ wkt,
                                        const float* __restrict__ bkv,
                                        float* __restrict__ ws, float* smem) {
  float* xs = smem;                    // [64][68]
  float* wt = smem + 4352;             // [64][136]
  const int mbase = vb * 64;
  const int rg = tid >> 4;             // rows rg*4 .. rg*4+3
  const int cg = tid & 15;             // cols cg*8 .. cg*8+7

  float acc[4][8];
#pragma unroll
  for (int i = 0; i < 4; ++i)
#pragma unroll
    for (int j = 0; j < 8; ++j) acc[i][j] = 0.f;

  for (int kt = 0; kt < 8; ++kt) {
    const int kb = kt * 64;
#pragma unroll
    for (int p = 0; p < 4; ++p) {
      int e = tid + p * 256;
      int r = e >> 4, kq = e & 15;
      int row = mbase + r;
      int t_ = row >> 11, n = row & 2047;
      int b = n >> 8, s = n & 255;
      float4 v = *(const float4*)(x + (size_t)((b * 16 + t_) * 256 + s) * 512 + kb + kq * 4);
      *(float4*)(xs + r * 68 + kq * 4) = v;
    }
#pragma unroll
    for (int p = 0; p < 8; ++p) {
      int e = tid + p * 256;
      int k = e >> 5, cq = e & 31;
      float4 v = *(const float4*)(wkt + (size_t)(kb + k) * 128 + cq * 4);
      *(float4*)(wt + k * 136 + cq * 4) = v;
    }
    __syncthreads();
#pragma unroll 2
    for (int kq = 0; kq < 16; ++kq) {
      float4 a0 = *(const float4*)(xs + (rg * 4 + 0) * 68 + kq * 4);
      float4 a1 = *(const float4*)(xs + (rg * 4 + 1) * 68 + kq * 4);
      float4 a2 = *(const float4*)(xs + (rg * 4 + 2) * 68 + kq * 4);
      float4 a3 = *(const float4*)(xs + (rg * 4 + 3) * 68 + kq * 4);
      const float* ap[4] = {(const float*)&a0, (const float*)&a1,
                            (const float*)&a2, (const float*)&a3};
#pragma unroll
      for (int kk = 0; kk < 4; ++kk) {
        const float* wp = wt + (kq * 4 + kk) * 136 + cg * 8;
        float4 b0 = *(const float4*)(wp);
        float4 b1 = *(const float4*)(wp + 4);
#pragma unroll
        for (int i = 0; i < 4; ++i) {
          float av = ap[i][kk];
          acc[i][0] += av * b0.x; acc[i][1] += av * b0.y;
          acc[i][2] += av * b0.z; acc[i][3] += av * b0.w;
          acc[i][4] += av * b1.x; acc[i][5] += av * b1.y;
          acc[i][6] += av * b1.z; acc[i][7] += av * b1.w;
        }
      }
    }
    __syncthreads();
  }
  float4 bb0 = *(const float4*)(bkv + cg * 8);
  float4 bb1 = *(const float4*)(bkv + cg * 8 + 4);
  float* kvout = ws + OFF_KV;
#pragma unroll
  for (int i = 0; i < 4; ++i) {
    float* op = kvout + (size_t)(mbase + rg * 4 + i) * 128 + cg * 8;
    float4 v0; v0.x = acc[i][0] + bb0.x; v0.y = acc[i][1] + bb0.y;
    v0.z = acc[i][2] + bb0.z; v0.w = acc[i][3] + bb0.w;
    float4 v1; v1.x = acc[i][4] + bb1.x; v1.y = acc[i][5] + bb1.y;
    v1.z = acc[i][6] + bb1.z; v1.w = acc[i][7] + bb1.w;
    *(float4*)(op) = v0;
    *(float4*)(op + 4) = v1;
  }
}

// attention partials (flash, key-split). vb: head(2b) | qtile(2b) | split(4b)
// 256 thr, 2 queries/thread, 128 keys/block. smem: kl[128][16] | vl[128][16].
__device__ __forceinline__ void attp_body(int vb, int tid, int t,
                                          const float* __restrict__ kvbase,
                                          const float* __restrict__ qbuf,
                                          float* __restrict__ pm,
                                          float* __restrict__ pl,
                                          float* __restrict__ pacc,
                                          float* smem) {
  const int head = vb & 3;
  const int qt = (vb >> 2) & 3;
  const int sp = vb >> 4;                 // 0..15
  float* kl = smem;
  float* vl = smem + 2048;
  const float* kvt = kvbase + (size_t)t * NTOK * 128;
  {
    int key = tid >> 1, q8 = (tid & 1) * 2;
    const float* base = kvt + (size_t)(sp * 128 + key) * 128 + head * 16;
    float4 k0 = ((const float4*)base)[q8];
    float4 k1 = ((const float4*)base)[q8 + 1];
    float4 v0 = ((const float4*)(base + 64))[q8];
    float4 v1 = ((const float4*)(base + 64))[q8 + 1];
    ((float4*)kl)[key * 4 + q8] = k0;
    ((float4*)kl)[key * 4 + q8 + 1] = k1;
    ((float4*)vl)[key * 4 + q8] = v0;
    ((float4*)vl)[key * 4 + q8 + 1] = v1;
  }
  const int i0 = qt * 512 + tid;
  const int i1 = i0 + 256;
  float q0[16], q1[16];
  {
    const float4* qp0 = (const float4*)(qbuf + (size_t)i0 * 64 + head * 16);
    const float4* qp1 = (const float4*)(qbuf + (size_t)i1 * 64 + head * 16);
#pragma unroll
    for (int r = 0; r < 4; ++r) {
      float4 a = qp0[r];
      q0[4 * r] = a.x; q0[4 * r + 1] = a.y; q0[4 * r + 2] = a.z; q0[4 * r + 3] = a.w;
      float4 b = qp1[r];
      q1[4 * r] = b.x; q1[4 * r + 1] = b.y; q1[4 * r + 2] = b.z; q1[4 * r + 3] = b.w;
    }
  }
  __syncthreads();
  float m0 = -INFINITY, l0 = 0.f, m1 = -INFINITY, l1 = 0.f;
  float acc0[16], acc1[16];
#pragma unroll
  for (int d = 0; d < 16; ++d) { acc0[d] = 0.f; acc1[d] = 0.f; }

#pragma unroll 2
  for (int ch = 0; ch < 8; ++ch) {
    float sc0[16], sc1[16];
#pragma unroll
    for (int j = 0; j < 16; ++j) {
      const float* kp = kl + (ch * 16 + j) * 16;
      float s0 = 0.f, s1 = 0.f;
#pragma unroll
      for (int d = 0; d < 16; ++d) { float kv_ = kp[d]; s0 += q0[d] * kv_; s1 += q1[d] * kv_; }
      sc0[j] = s0 * SCALE; sc1[j] = s1 * SCALE;
    }
    float mb0 = sc0[0], mb1 = sc1[0];
#pragma unroll
    for (int j = 1; j < 16; ++j) { mb0 = fmaxf(mb0, sc0[j]); mb1 = fmaxf(mb1, sc1[j]); }
    float mn0 = fmaxf(m0, mb0), mn1 = fmaxf(m1, mb1);
    float r0 = exp2f((m0 - mn0) * LOG2E), r1 = exp2f((m1 - mn1) * LOG2E);
    l0 *= r0; l1 *= r1;
#pragma unroll
    for (int d = 0; d < 16; ++d) { acc0[d] *= r0; acc1[d] *= r1; }
#pragma unroll
    for (int j = 0; j < 16; ++j) {
      float w0 = exp2f((sc0[j] - mn0) * LOG2E), w1 = exp2f((sc1[j] - mn1) * LOG2E);
      l0 += w0; l1 += w1; sc0[j] = w0; sc1[j] = w1;
    }
#pragma unroll
    for (int j = 0; j < 16; ++j) {
      const float* vp = vl + (ch * 16 + j) * 16;
      float w0 = sc0[j], w1 = sc1[j];
#pragma unroll
      for (int d = 0; d < 16; ++d) { float vv = vp[d]; acc0[d] += w0 * vv; acc1[d] += w1 * vv; }
    }
    m0 = mn0; m1 = mn1;
  }
  const int pbase = (head * NSPLIT + sp) * NTOK;
  pm[pbase + i0] = m0; pm[pbase + i1] = m1;
  pl[pbase + i0] = l0; pl[pbase + i1] = l1;
  float4* pa0 = (float4*)(pacc + (size_t)(pbase + i0) * 16);
  float4* pa1 = (float4*)(pacc + (size_t)(pbase + i1) * 16);
#pragma unroll
  for (int r = 0; r < 4; ++r) {
    float4 v0; v0.x = acc0[4 * r]; v0.y = acc0[4 * r + 1]; v0.z = acc0[4 * r + 2]; v0.w = acc0[4 * r + 3];
    pa0[r] = v0;
    float4 v1; v1.x = acc1[4 * r]; v1.y = acc1[4 * r + 1]; v1.z = acc1[4 * r + 2]; v1.w = acc1[4 * r + 3];
    pa1[r] = v1;
  }
}

// combine partials -> att ; su = h@A.T + att@Wo.T + bo ; LIF-S; q(t+1).
// thr passed in (precomputed chain). smem: As|Wqs|Wos|att_s|hv_s|sp_s.
__device__ __forceinline__ void combine_body(
    int vb, int tid, int t, float thr,
    const float* __restrict__ A, const float* __restrict__ Wq,
    const float* __restrict__ bq, const float* __restrict__ Wo,
    const float* __restrict__ bo, float* __restrict__ ws,
    float* smem, int* scnt) {
  float* As  = smem;                     // [64][68]
  float* Wqs = smem + 4352;
  float* Wos = smem + 8704;
  float* att_s = smem + 13056;           // [4][64]
  float* hv_s  = smem + 13312;
  float* sp_s  = smem + 13568;
#pragma unroll
  for (int p = 0; p < 4; ++p) {
    int e = tid + p * 256;
    int c = e >> 4, kq = e & 15;
    *(float4*)(As + c * 68 + kq * 4)  = *(const float4*)(A + c * 64 + kq * 4);
    *(float4*)(Wqs + c * 68 + kq * 4) = *(const float4*)(Wq + c * 64 + kq * 4);
    *(float4*)(Wos + c * 68 + kq * 4) = *(const float4*)(Wo + c * 64 + kq * 4);
  }
  if (tid == 0) *scnt = 0;

  const float* pm = ws + OFF_PM;
  const float* pl = ws + OFF_PL;
  const float* pacc = ws + OFF_PACC;
  float* h = ws + OFF_H;
  float* sv = ws + OFF_SV;
  float* qb = ws + OFF_Q;
  int* cnt = (int*)(ws + OFF_CNT);

  const int lane = tid & 63, w = tid >> 6;
  const int n = vb * 4 + w;
  const int head = lane >> 4, d = lane & 15;
  const int pb = head * NSPLIT * NTOK + n;

  float mstar = -INFINITY;
  for (int s = 0; s < NSPLIT; ++s) mstar = fmaxf(mstar, pm[pb + s * NTOK]);
  float lst = 0.f, av = 0.f;
  for (int s = 0; s < NSPLIT; ++s) {
    float e = exp2f((pm[pb + s * NTOK] - mstar) * LOG2E);
    lst += e * pl[pb + s * NTOK];
    av += e * pacc[(size_t)(pb + s * NTOK) * 16 + d];
  }
  att_s[w * 64 + lane] = av / lst;
  float hv = h[n * 64 + lane];
  hv_s[w * 64 + lane] = hv;
  __syncthreads();

  const float* Ar = As + lane * 68;
  const float* Wor = Wos + lane * 68;
  float st = 0.f, wo = 0.f;
#pragma unroll
  for (int kq = 0; kq < 16; ++kq) {
    float4 wa = *(const float4*)(Ar + kq * 4);
    float4 wb = *(const float4*)(Wor + kq * 4);
    float4 hb = *(const float4*)(hv_s + w * 64 + kq * 4);
    float4 ab = *(const float4*)(att_s + w * 64 + kq * 4);
    st += hb.x * wa.x; st += hb.y * wa.y; st += hb.z * wa.z; st += hb.w * wa.w;
    wo += ab.x * wb.x; wo += ab.y * wb.y; wo += ab.z * wb.z; wo += ab.w * wb.w;
  }
  float su = st + wo + bo[lane];

  float svo = sv[n * 64 + lane];
  float vpot = svo * MEMDECAY + su;
  float spk = (vpot >= thr) ? 1.f : 0.f;
  h[n * 64 + lane] = spk;
  sv[n * 64 + lane] = vpot * (1.f - spk);
  sp_s[w * 64 + lane] = spk;
  unsigned long long sm = __ballot(spk > 0.5f);

  const float* Wqr = Wqs + lane * 68;
  float qv = 0.f;
#pragma unroll
  for (int kq = 0; kq < 16; ++kq) {
    float4 wq = *(const float4*)(Wqr + kq * 4);
    float4 sb = *(const float4*)(sp_s + w * 64 + kq * 4);
    qv += sb.x * wq.x; qv += sb.y * wq.y; qv += sb.z * wq.z; qv += sb.w * wq.w;
  }
  qb[n * 64 + lane] = qv + bq[lane];

  if (lane == 0) atomicAdd(scnt, __popcll(sm));
  __syncthreads();
  if (tid == 0) atomicAdd(&cnt[t], *scnt);
}

// LIF-O: out_pot = h2 @ C.T with fused LIF epilogue. vb in [0,256).
// smem: hs[64][68] | cts[64][68].
__device__ __forceinline__ void out_body(
    int vb, int tid, int t, float thr, float* __restrict__ out,
    float* __restrict__ ws, float* smem, int* scnt) {
  float* hs = smem;
  float* cts = smem + 4352;
  const int nt = vb >> 3;                  // token tile 0..31
  const int ct = vb & 7;                   // channel tile 0..7
  const float* h = ws + OFF_H;
  const float* Ct = ws + OFF_CT;
  float* ov = ws + OFF_OV;
  int* cnt = (int*)(ws + OFF_CNT);

#pragma unroll
  for (int p = 0; p < 4; ++p) {
    int e = tid + p * 256;
    int r = e >> 4, kq = e & 15;
    float4 v = *(const float4*)(h + (size_t)(nt * 64 + r) * 64 + kq * 4);
    *(float4*)(hs + r * 68 + kq * 4) = v;
  }
#pragma unroll
  for (int p = 0; p < 4; ++p) {
    int e = tid + p * 256;
    int k = e >> 4, cq = e & 15;
    float4 v = *(const float4*)(Ct + (size_t)k * 512 + ct * 64 + cq * 4);
    *(float4*)(cts + k * 68 + cq * 4) = v;
  }
  if (tid == 0) *scnt = 0;
  __syncthreads();

  const int tr = tid >> 4, tc = tid & 15;
  float acc[4][4];
#pragma unroll
  for (int i = 0; i < 4; ++i)
#pragma unroll
    for (int j = 0; j < 4; ++j) acc[i][j] = 0.f;

#pragma unroll 4
  for (int k4 = 0; k4 < 16; ++k4) {
    float4 hv[4];
#pragma unroll
    for (int i = 0; i < 4; ++i) hv[i] = *(const float4*)(hs + (tr + i * 16) * 68 + k4 * 4);
#pragma unroll
    for (int kk = 0; kk < 4; ++kk) {
      float4 c = *(const float4*)(cts + (k4 * 4 + kk) * 68 + tc * 4);
#pragma unroll
      for (int i = 0; i < 4; ++i) {
        float hvv = ((const float*)&hv[i])[kk];
        acc[i][0] += hvv * c.x;
        acc[i][1] += hvv * c.y;
        acc[i][2] += hvv * c.z;
        acc[i][3] += hvv * c.w;
      }
    }
  }

  int mycount = 0;
#pragma unroll
  for (int i = 0; i < 4; ++i) {
    int n = nt * 64 + tr + i * 16;
    int b = n >> 8, s = n & 255;
    size_t coff = (size_t)ct * 64 + tc * 4;
    float* ovp = ov + (size_t)n * 512 + coff;
    float* outp = out + ((size_t)(b * 16 + t) * 256 + s) * 512 + coff;
    float4 o = *(float4*)ovp;
    float v0 = o.x * MEMDECAY + acc[i][0];
    float v1 = o.y * MEMDECAY + acc[i][1];
    float v2 = o.z * MEMDECAY + acc[i][2];
    float v3 = o.w * MEMDECAY + acc[i][3];
    float s0 = (v0 >= thr) ? 1.f : 0.f;
    float s1 = (v1 >= thr) ? 1.f : 0.f;
    float s2 = (v2 >= thr) ? 1.f : 0.f;
    float s3 = (v3 >= thr) ? 1.f : 0.f;
    float4 sp; sp.x = s0; sp.y = s1; sp.z = s2; sp.w = s3;
    *(float4*)outp = sp;
    float4 nv; nv.x = v0 * (1.f - s0); nv.y = v1 * (1.f - s1);
    nv.z = v2 * (1.f - s2); nv.w = v3 * (1.f - s3);
    *(float4*)ovp = nv;
    mycount += (int)(s0 + s1 + s2 + s3);
  }
  atomicAdd(scnt, mycount);
  __syncthreads();
  if (tid == 0) atomicAdd(&cnt[16 + t], *scnt);
}

// ---------------------------------------------------------------------------
// persistent cooperative kernel: everything in one dispatch
// ---------------------------------------------------------------------------
__global__ __launch_bounds__(256, 2) void mega_kernel(
    const float* __restrict__ x, const float* __restrict__ A,
    const float* __restrict__ C, const float* __restrict__ Wq,
    const float* __restrict__ bq, const float* __restrict__ Wkv,
    const float* __restrict__ bkv, const float* __restrict__ Wo,
    const float* __restrict__ bo, const float* __restrict__ thr_s0,
    const float* __restrict__ thr_o0, float* __restrict__ out,
    float* __restrict__ ws) {
  __shared__ float smem[SMEM_FLOATS];
  __shared__ int scnt;
  cg::grid_group grid = cg::this_grid();
  const int blk = blockIdx.x;
  const int tid = threadIdx.x;
  const int G = gridDim.x;

  init_body(blk * 256 + tid, G * 256, bq, C, Wkv, ws);
  grid.sync();

  for (int vb = blk; vb < 512; vb += G) {
    kv_body(vb, tid, x, ws + OFF_WT, bkv, ws, smem);
    __syncthreads();
  }
  grid.sync();

  for (int vb = blk; vb < 256; vb += G) {
    attp_body(vb, tid, 0, ws + OFF_KV, ws + OFF_Q,
              ws + OFF_PM, ws + OFF_PL, ws + OFF_PACC, smem);
    __syncthreads();
  }
  grid.sync();

  int* cnt = (int*)(ws + OFF_CNT);
  float thr_s = thr_s0[0];
  float thr_o = thr_o0[0];
  for (int t = 0; t < TSTEPS; ++t) {
    for (int vb = blk; vb < 512; vb += G) {
      combine_body(vb, tid, t, thr_s, A, Wq, bq, Wo, bo, ws, smem, &scnt);
      __syncthreads();
    }
    grid.sync();
    {
      int c = __hip_atomic_load(&cnt[t], __ATOMIC_RELAXED, __HIP_MEMORY_SCOPE_AGENT);
      thr_s = fmaxf(thr_s + 0.1f * ((float)c * (1.f / 131072.f) - 0.02f), 0.5f);
    }
    for (int vb = blk; vb < 512; vb += G) {
      if (vb < 256) {
        out_body(vb, tid, t, thr_o, out, ws, smem, &scnt);
      } else if (t < TSTEPS - 1) {
        attp_body(vb - 256, tid, t + 1, ws + OFF_KV, ws + OFF_Q,
                  ws + OFF_PM, ws + OFF_PL, ws + OFF_PACC, smem);
      }
      __syncthreads();
    }
    grid.sync();
    {
      int c = __hip_atomic_load(&cnt[16 + t], __ATOMIC_RELAXED, __HIP_MEMORY_SCOPE_AGENT);
      thr_o = fmaxf(thr_o + 0.1f * ((float)c * (1.f / 1048576.f) - 0.02f), 0.5f);
    }
  }
}

// ---------------------------------------------------------------------------
// fallback wrappers (R3 multi-kernel path)
// ---------------------------------------------------------------------------
__global__ __launch_bounds__(256) void init_kernel(const float* __restrict__ bq,
                                                   const float* __restrict__ C,
                                                   const float* __restrict__ Wkv,
                                                   float* __restrict__ ws) {
  init_body(blockIdx.x * 256 + threadIdx.x, 2177 * 256, bq, C, Wkv, ws);
}

__global__ __launch_bounds__(256) void kv_gemm_kernel(const float* __restrict__ x,
                                                      const float* __restrict__ wkt,
                                                      const float* __restrict__ bkv,
                                                      float* __restrict__ ws) {
  __shared__ float smem[SMEM_FLOATS];
  kv_body(blockIdx.x, threadIdx.x, x, wkt, bkv, ws, smem);
}

__global__ __launch_bounds__(256) void attp_kernel(int t, float* __restrict__ ws) {
  __shared__ float smem[4096];
  attp_body(blockIdx.x, threadIdx.x, t, ws + OFF_KV, ws + OFF_Q,
            ws + OFF_PM, ws + OFF_PL, ws + OFF_PACC, smem);
}

__global__ __launch_bounds__(256) void combine_lifs_kernel(
    int t, const float* __restrict__ A, const float* __restrict__ Wq,
    const float* __restrict__ bq, const float* __restrict__ Wo,
    const float* __restrict__ bo, const float* __restrict__ thr_s0,
    float* __restrict__ ws) {
  __shared__ float smem[SMEM_FLOATS];
  __shared__ int scnt;
  int* cnt = (int*)(ws + OFF_CNT);
  float thr = thr_s0[0];
  for (int i = 0; i < t; ++i) {
    float mean = (float)cnt[i] * (1.f / 131072.f);
    thr = fmaxf(thr + 0.1f * (mean - 0.02f), 0.5f);
  }
  combine_body(blockIdx.x, threadIdx.x, t, thr, A, Wq, bq, Wo, bo, ws, smem, &scnt);
}

__global__ __launch_bounds__(256) void fused_out_attp_kernel(
    int t, const float* __restrict__ thr_o0, float* __restrict__ out,
    float* __restrict__ ws) {
  __shared__ float smem[SMEM_FLOATS];
  __shared__ int scnt;
  const int blk = blockIdx.x;
  if (blk >= 256) {
    attp_body(blk - 256, threadIdx.x, t + 1, ws + OFF_KV, ws + OFF_Q,
              ws + OFF_PM, ws + OFF_PL, ws + OFF_PACC, smem);
    return;
  }
  int* cnt = (int*)(ws + OFF_CNT);
  float thr = thr_o0[0];
  for (int i = 0; i < t; ++i) {
    float mean = (float)cnt[16 + i] * (1.f / 1048576.f);
    thr = fmaxf(thr + 0.1f * (mean - 0.02f), 0.5f);
  }
  out_body(blk, threadIdx.x, t, thr, out, ws, smem, &scnt);
}

// ---------------------------------------------------------------------------
extern "C" void kernel_launch(void* const* d_in, const int* in_sizes, int n_in,
                              void* d_out, int out_size, void* d_ws, size_t ws_size,
                              hipStream_t stream) {
  const float* x    = (const float*)d_in[0];
  const float* A    = (const float*)d_in[1];
  const float* C    = (const float*)d_in[2];
  const float* Wq   = (const float*)d_in[3];
  const float* bq   = (const float*)d_in[4];
  const float* Wkv  = (const float*)d_in[5];
  const float* bkv  = (const float*)d_in[6];
  const float* Wo   = (const float*)d_in[7];
  const float* bo   = (const float*)d_in[8];
  const float* th_s = (const float*)d_in[9];
  const float* th_o = (const float*)d_in[10];
  float* out = (float*)d_out;
  float* ws = (float*)d_ws;

  int nb = 0;
  hipError_t qe = hipOccupancyMaxActiveBlocksPerMultiprocessor(&nb, mega_kernel, 256, 0);
  hipError_t le = hipErrorUnknown;
  if (qe == hipSuccess && nb > 0) {
    int G = nb * 256;                      // 256 CUs on MI355X
    if (G > 512) G = 512;
    void* args[] = {(void*)&x, (void*)&A, (void*)&C, (void*)&Wq, (void*)&bq,
                    (void*)&Wkv, (void*)&bkv, (void*)&Wo, (void*)&bo,
                    (void*)&th_s, (void*)&th_o, (void*)&out, (void*)&ws};
    le = hipLaunchCooperativeKernel(mega_kernel, dim3(G), dim3(256), args, 0, stream);
  }
  if (le != hipSuccess) {
    // fallback: R3 multi-kernel schedule
    init_kernel<<<dim3(2177), dim3(256), 0, stream>>>(bq, C, Wkv, ws);
    kv_gemm_kernel<<<dim3(512), dim3(256), 0, stream>>>(x, ws + OFF_WT, bkv, ws);
    attp_kernel<<<dim3(256), dim3(256), 0, stream>>>(0, ws);
    for (int t = 0; t < TSTEPS; ++t) {
      combine_lifs_kernel<<<dim3(512), dim3(256), 0, stream>>>(t, A, Wq, bq, Wo, bo, th_s, ws);
      int g = (t < TSTEPS - 1) ? 512 : 256;
      fused_out_attp_kernel<<<dim3(g), dim3(256), 0, stream>>>(t, th_o, out, ws);
    }
  }
}

// Round 3
// 1195.250 us; speedup vs baseline: 1.9718x; 1.9718x over previous
//
#include <hip/hip_runtime.h>
#include <math.h>

// ---------------------------------------------------------------------------
// AttentionalSpikingSSMLayer  (B=8, T=16, S=256, D=512, DS=64, H=4, dh=16)
// All compute fp32 (no fp32 MFMA on CDNA4; Heaviside spikes need fp32 margin).
// R1: LIF-O ballot-gather -> dense LDS GEMM (1714 -> 1258 us).
// R2: kv_gemm vectorized LDS; combine gathers -> dense b128 dots.
// R3: NSPLIT 32->16; expf -> exp2f; LIF-O b128 LDS reads. (1143 us measured)
// R4: cooperative mega-kernel FAILED (2767 us): grid.sync = per-XCD L2
//     invalidate+flush (~46 us each, FETCH 288MB). Reverted.
// R5: packed fp32 (v_pk_fma_f32 via float2 + __builtin_elementwise_fma) in
//     kv_gemm / attp QK+PV+rescale / LIF-O GEMM. Packing over output index
//     where possible (bit-identical); QK packs over k (even/odd partials,
//     ~1ulp reorder, same scale as R3's accepted reorder).
// ---------------------------------------------------------------------------

#define NTOK   2048          // B*S
#define TSTEPS 16
#define NSPLIT 16            // key splits for flash partials (128 keys each)

#define MEMDECAY ((float)0.6065306597126334)
#define SCALE    0.25f       // 1/sqrt(dh)
#define LOG2E    1.4426950408889634f

typedef float v2f __attribute__((ext_vector_type(2)));
__device__ __forceinline__ v2f pkfma(v2f a, v2f b, v2f c) {
  return __builtin_elementwise_fma(a, b, c);   // -> v_pk_fma_f32 on gfx950
}

// workspace layout (float offsets)
#define OFF_KV   ((size_t)0)                      // 16*2048*128
#define OFF_PACC ((size_t)4194304)
#define OFF_OV   ((size_t)8388608)                // 2048*512
#define OFF_H    ((size_t)9437184)                // 2048*64
#define OFF_SV   ((size_t)9568256)
#define OFF_Q    ((size_t)9699328)
#define OFF_PM   ((size_t)9830400)
#define OFF_PL   ((size_t)10092544)
#define OFF_CT   ((size_t)10354688)               // 64*512 (C transposed)
#define OFF_CNT  ((size_t)10387456)               // 32 ints: [0..15]=s, [16..31]=o
#define OFF_WT   ((size_t)10387488)               // 512*128 (Wkv transposed)

// ---------------------------------------------------------------------------
// init: zero ov+h+sv, q <- bq, C_t transpose, Wkv_t transpose, zero counters.
// ---------------------------------------------------------------------------
__global__ __launch_bounds__(256) void init_kernel(const float* __restrict__ bq,
                                                   const float* __restrict__ C,
                                                   const float* __restrict__ Wkv,
                                                   float* __restrict__ ws) {
  int i = blockIdx.x * 256 + threadIdx.x;
  if (i < 327680) {                       // zero ov+h+sv (float4)
    float4 z = {0.f, 0.f, 0.f, 0.f};
    ((float4*)(ws + OFF_OV))[i] = z;
    return;
  }
  i -= 327680;
  if (i < 131072) { ws[OFF_Q + i] = bq[i & 63]; return; }
  i -= 131072;
  if (i < 32768) {                        // C_t[k][c] = C[c][k]
    int k = i >> 9, c = i & 511;
    ws[OFF_CT + i] = C[c * 64 + k];
    return;
  }
  i -= 32768;
  if (i < 65536) {                        // Wkv_t[k][o] = Wkv[o][k]
    int k = i >> 7, o = i & 127;
    ws[OFF_WT + i] = Wkv[o * 512 + k];
    return;
  }
  i -= 65536;
  if (i < 32) ((int*)(ws + OFF_CNT))[i] = 0;
}

// ---------------------------------------------------------------------------
// KV projection: kv[t][n][o] = sum_d x[row][d]*Wkv[o][d] + bkv[o]
// M=32768 rows, K=512, Nc=128. Block: 64 rows x 128 cols, thread: 4x8.
// Inner loop packed over output cols (bit-identical k-order).
// ---------------------------------------------------------------------------
__global__ __launch_bounds__(256) void kv_gemm_kernel(const float* __restrict__ x,
                                                      const float* __restrict__ wkt,
                                                      const float* __restrict__ bkv,
                                                      float* __restrict__ ws) {
  __shared__ float xs[64 * 68];        // rows x k, stride 68
  __shared__ float wt[64 * 136];       // k x cols, stride 136
  const int tid = threadIdx.x;
  const int mbase = blockIdx.x * 64;
  const int rg = tid >> 4;             // rows rg*4 .. rg*4+3
  const int cg = tid & 15;             // cols cg*8 .. cg*8+7

  v2f acc[4][4];
#pragma unroll
  for (int i = 0; i < 4; ++i)
#pragma unroll
    for (int j = 0; j < 4; ++j) acc[i][j] = (v2f){0.f, 0.f};

  for (int kt = 0; kt < 8; ++kt) {
    const int kb = kt * 64;
#pragma unroll
    for (int p = 0; p < 4; ++p) {
      int e = tid + p * 256;
      int r = e >> 4, kq = e & 15;
      int row = mbase + r;
      int t_ = row >> 11, n = row & 2047;
      int b = n >> 8, s = n & 255;
      float4 v = *(const float4*)(x + (size_t)((b * 16 + t_) * 256 + s) * 512 + kb + kq * 4);
      *(float4*)(xs + r * 68 + kq * 4) = v;
    }
#pragma unroll
    for (int p = 0; p < 8; ++p) {
      int e = tid + p * 256;
      int k = e >> 5, cq = e & 31;
      float4 v = *(const float4*)(wkt + (size_t)(kb + k) * 128 + cq * 4);
      *(float4*)(wt + k * 136 + cq * 4) = v;
    }
    __syncthreads();
#pragma unroll 2
    for (int kq = 0; kq < 16; ++kq) {
      float4 a0 = *(const float4*)(xs + (rg * 4 + 0) * 68 + kq * 4);
      float4 a1 = *(const float4*)(xs + (rg * 4 + 1) * 68 + kq * 4);
      float4 a2 = *(const float4*)(xs + (rg * 4 + 2) * 68 + kq * 4);
      float4 a3 = *(const float4*)(xs + (rg * 4 + 3) * 68 + kq * 4);
      const float* ap[4] = {(const float*)&a0, (const float*)&a1,
                            (const float*)&a2, (const float*)&a3};
#pragma unroll
      for (int kk = 0; kk < 4; ++kk) {
        const float* wp = wt + (kq * 4 + kk) * 136 + cg * 8;
        float4 b0 = *(const float4*)(wp);
        float4 b1 = *(const float4*)(wp + 4);
        v2f bb[4] = {{b0.x, b0.y}, {b0.z, b0.w}, {b1.x, b1.y}, {b1.z, b1.w}};
#pragma unroll
        for (int i = 0; i < 4; ++i) {
          float av = ap[i][kk];
          v2f avv = {av, av};
#pragma unroll
          for (int j = 0; j < 4; ++j) acc[i][j] = pkfma(avv, bb[j], acc[i][j]);
        }
      }
    }
    __syncthreads();
  }
  float4 bb0 = *(const float4*)(bkv + cg * 8);
  float4 bb1 = *(const float4*)(bkv + cg * 8 + 4);
  float* kvout = ws + OFF_KV;
#pragma unroll
  for (int i = 0; i < 4; ++i) {
    float* op = kvout + (size_t)(mbase + rg * 4 + i) * 128 + cg * 8;
    float4 v0; v0.x = acc[i][0].x + bb0.x; v0.y = acc[i][0].y + bb0.y;
    v0.z = acc[i][1].x + bb0.z; v0.w = acc[i][1].y + bb0.w;
    float4 v1; v1.x = acc[i][2].x + bb1.x; v1.y = acc[i][2].y + bb1.y;
    v1.z = acc[i][3].x + bb1.z; v1.w = acc[i][3].y + bb1.w;
    *(float4*)(op) = v0;
    *(float4*)(op + 4) = v1;
  }
}

// ---------------------------------------------------------------------------
// attention partials (flash, key-split). blk: head(2b) | qtile(2b) | split(4b)
// 256 thr, 2 queries/thread, 128 keys/block. QK packed over k (even/odd
// partials); PV + rescale packed over d (bit-identical).
// ---------------------------------------------------------------------------
__device__ __forceinline__ void attp_body(int blk, int tid, int t,
                                          const float* __restrict__ kvbase,
                                          const float* __restrict__ qbuf,
                                          float* __restrict__ pm,
                                          float* __restrict__ pl,
                                          float* __restrict__ pacc,
                                          float* smem) {
  const int head = blk & 3;
  const int qt = (blk >> 2) & 3;
  const int sp = blk >> 4;                 // 0..15
  float* kl = smem;                        // [128][16]
  float* vl = smem + 2048;
  const float* kvt = kvbase + (size_t)t * NTOK * 128;
  {
    int key = tid >> 1, q8 = (tid & 1) * 2;
    const float* base = kvt + (size_t)(sp * 128 + key) * 128 + head * 16;
    float4 k0 = ((const float4*)base)[q8];
    float4 k1 = ((const float4*)base)[q8 + 1];
    float4 v0 = ((const float4*)(base + 64))[q8];
    float4 v1 = ((const float4*)(base + 64))[q8 + 1];
    ((float4*)kl)[key * 4 + q8] = k0;
    ((float4*)kl)[key * 4 + q8 + 1] = k1;
    ((float4*)vl)[key * 4 + q8] = v0;
    ((float4*)vl)[key * 4 + q8 + 1] = v1;
  }
  const int i0 = qt * 512 + tid;
  const int i1 = i0 + 256;
  v2f q0v[8], q1v[8];
  {
    const float4* qp0 = (const float4*)(qbuf + (size_t)i0 * 64 + head * 16);
    const float4* qp1 = (const float4*)(qbuf + (size_t)i1 * 64 + head * 16);
#pragma unroll
    for (int r = 0; r < 4; ++r) {
      float4 a = qp0[r];
      q0v[2 * r] = (v2f){a.x, a.y}; q0v[2 * r + 1] = (v2f){a.z, a.w};
      float4 b = qp1[r];
      q1v[2 * r] = (v2f){b.x, b.y}; q1v[2 * r + 1] = (v2f){b.z, b.w};
    }
  }
  __syncthreads();
  float m0 = -INFINITY, l0 = 0.f, m1 = -INFINITY, l1 = 0.f;
  v2f acc0[8], acc1[8];
#pragma unroll
  for (int d = 0; d < 8; ++d) { acc0[d] = (v2f){0.f, 0.f}; acc1[d] = (v2f){0.f, 0.f}; }

#pragma unroll 2
  for (int ch = 0; ch < 8; ++ch) {
    float sc0[16], sc1[16];
#pragma unroll
    for (int j = 0; j < 16; ++j) {
      const v2f* kp = (const v2f*)(kl + (ch * 16 + j) * 16);
      v2f s0 = {0.f, 0.f}, s1 = {0.f, 0.f};
#pragma unroll
      for (int d = 0; d < 8; ++d) {
        v2f kv_ = kp[d];
        s0 = pkfma(q0v[d], kv_, s0);
        s1 = pkfma(q1v[d], kv_, s1);
      }
      sc0[j] = (s0.x + s0.y) * SCALE;
      sc1[j] = (s1.x + s1.y) * SCALE;
    }
    float mb0 = sc0[0], mb1 = sc1[0];
#pragma unroll
    for (int j = 1; j < 16; ++j) { mb0 = fmaxf(mb0, sc0[j]); mb1 = fmaxf(mb1, sc1[j]); }
    float mn0 = fmaxf(m0, mb0), mn1 = fmaxf(m1, mb1);
    float r0 = exp2f((m0 - mn0) * LOG2E), r1 = exp2f((m1 - mn1) * LOG2E);
    l0 *= r0; l1 *= r1;
    v2f r0v = {r0, r0}, r1v = {r1, r1};
#pragma unroll
    for (int d = 0; d < 8; ++d) { acc0[d] = acc0[d] * r0v; acc1[d] = acc1[d] * r1v; }
#pragma unroll
    for (int j = 0; j < 16; ++j) {
      float w0 = exp2f((sc0[j] - mn0) * LOG2E), w1 = exp2f((sc1[j] - mn1) * LOG2E);
      l0 += w0; l1 += w1; sc0[j] = w0; sc1[j] = w1;
    }
#pragma unroll
    for (int j = 0; j < 16; ++j) {
      const v2f* vp = (const v2f*)(vl + (ch * 16 + j) * 16);
      v2f w0v = {sc0[j], sc0[j]}, w1v = {sc1[j], sc1[j]};
#pragma unroll
      for (int d = 0; d < 8; ++d) {
        v2f vv = vp[d];
        acc0[d] = pkfma(w0v, vv, acc0[d]);
        acc1[d] = pkfma(w1v, vv, acc1[d]);
      }
    }
    m0 = mn0; m1 = mn1;
  }
  const int pbase = (head * NSPLIT + sp) * NTOK;
  pm[pbase + i0] = m0; pm[pbase + i1] = m1;
  pl[pbase + i0] = l0; pl[pbase + i1] = l1;
  float4* pa0 = (float4*)(pacc + (size_t)(pbase + i0) * 16);
  float4* pa1 = (float4*)(pacc + (size_t)(pbase + i1) * 16);
#pragma unroll
  for (int r = 0; r < 4; ++r) {
    float4 v0; v0.x = acc0[2 * r].x; v0.y = acc0[2 * r].y;
    v0.z = acc0[2 * r + 1].x; v0.w = acc0[2 * r + 1].y;
    pa0[r] = v0;
    float4 v1; v1.x = acc1[2 * r].x; v1.y = acc1[2 * r].y;
    v1.z = acc1[2 * r + 1].x; v1.w = acc1[2 * r + 1].y;
    pa1[r] = v1;
  }
}

__global__ __launch_bounds__(256) void attp_kernel(int t, float* __restrict__ ws) {
  __shared__ float smem[4096];
  attp_body(blockIdx.x, threadIdx.x, t, ws + OFF_KV, ws + OFF_Q,
            ws + OFF_PM, ws + OFF_PL, ws + OFF_PACC, smem);
}

// ---------------------------------------------------------------------------
// combine partials -> att ; su = h@A.T + att@Wo.T + bo ; LIF-S; q(t+1).
// (kept scalar: tiny compute, preserves exact numerics of R3)
// ---------------------------------------------------------------------------
__global__ __launch_bounds__(256) void combine_lifs_kernel(
    int t, const float* __restrict__ A, const float* __restrict__ Wq,
    const float* __restrict__ bq, const float* __restrict__ Wo,
    const float* __restrict__ bo, const float* __restrict__ thr_s0,
    float* __restrict__ ws) {
  __shared__ float As[64 * 68], Wqs[64 * 68], Wos[64 * 68];
  __shared__ float att_s[4][64], hv_s[4][64], sp_s[4][64];
  __shared__ int scnt;
  const int tid = threadIdx.x;
#pragma unroll
  for (int p = 0; p < 4; ++p) {
    int e = tid + p * 256;
    int c = e >> 4, kq = e & 15;
    *(float4*)(As + c * 68 + kq * 4)  = *(const float4*)(A + c * 64 + kq * 4);
    *(float4*)(Wqs + c * 68 + kq * 4) = *(const float4*)(Wq + c * 64 + kq * 4);
    *(float4*)(Wos + c * 68 + kq * 4) = *(const float4*)(Wo + c * 64 + kq * 4);
  }
  if (tid == 0) scnt = 0;

  const float* pm = ws + OFF_PM;
  const float* pl = ws + OFF_PL;
  const float* pacc = ws + OFF_PACC;
  float* h = ws + OFF_H;
  float* sv = ws + OFF_SV;
  float* qb = ws + OFF_Q;
  int* cnt = (int*)(ws + OFF_CNT);

  const int lane = tid & 63, w = tid >> 6;
  const int n = blockIdx.x * 4 + w;
  const int head = lane >> 4, d = lane & 15;
  const int pb = head * NSPLIT * NTOK + n;

  float mstar = -INFINITY;
  for (int s = 0; s < NSPLIT; ++s) mstar = fmaxf(mstar, pm[pb + s * NTOK]);
  float lst = 0.f, av = 0.f;
  for (int s = 0; s < NSPLIT; ++s) {
    float e = exp2f((pm[pb + s * NTOK] - mstar) * LOG2E);
    lst += e * pl[pb + s * NTOK];
    av += e * pacc[(size_t)(pb + s * NTOK) * 16 + d];
  }
  att_s[w][lane] = av / lst;
  float hv = h[n * 64 + lane];
  hv_s[w][lane] = hv;
  __syncthreads();

  const float* Ar = As + lane * 68;
  const float* Wor = Wos + lane * 68;
  float st = 0.f, wo = 0.f;
#pragma unroll
  for (int kq = 0; kq < 16; ++kq) {
    float4 wa = *(const float4*)(Ar + kq * 4);
    float4 wb = *(const float4*)(Wor + kq * 4);
    float4 hb = *(const float4*)(&hv_s[w][kq * 4]);
    float4 ab = *(const float4*)(&att_s[w][kq * 4]);
    st += hb.x * wa.x; st += hb.y * wa.y; st += hb.z * wa.z; st += hb.w * wa.w;
    wo += ab.x * wb.x; wo += ab.y * wb.y; wo += ab.z * wb.z; wo += ab.w * wb.w;
  }
  float su = st + wo + bo[lane];

  float thr = thr_s0[0];
  const float inv = 1.0f / 131072.0f;
  for (int i = 0; i < t; ++i) {
    float mean = (float)cnt[i] * inv;
    thr = fmaxf(thr + 0.1f * (mean - 0.02f), 0.5f);
  }
  float svo = sv[n * 64 + lane];
  float vpot = svo * MEMDECAY + su;
  float spk = (vpot >= thr) ? 1.f : 0.f;
  h[n * 64 + lane] = spk;
  sv[n * 64 + lane] = vpot * (1.f - spk);
  sp_s[w][lane] = spk;
  unsigned long long sm = __ballot(spk > 0.5f);

  const float* Wqr = Wqs + lane * 68;
  float qv = 0.f;
#pragma unroll
  for (int kq = 0; kq < 16; ++kq) {
    float4 wq = *(const float4*)(Wqr + kq * 4);
    float4 sb = *(const float4*)(&sp_s[w][kq * 4]);
    qv += sb.x * wq.x; qv += sb.y * wq.y; qv += sb.z * wq.z; qv += sb.w * wq.w;
  }
  qb[n * 64 + lane] = qv + bq[lane];

  if (lane == 0) atomicAdd(&scnt, __popcll(sm));
  __syncthreads();
  if (tid == 0) atomicAdd(&cnt[t], scnt);
}

// ---------------------------------------------------------------------------
// LIF-O: out_pot = h2 @ C.T with fused LIF epilogue; fused with attp(t+1)
// in blocks [256, 512). GEMM inner packed over output cols (bit-identical).
// ---------------------------------------------------------------------------
__global__ __launch_bounds__(256) void fused_out_attp_kernel(
    int t, const float* __restrict__ thr_o0, float* __restrict__ out,
    float* __restrict__ ws) {
  __shared__ float smem[64 * 68 + 64 * 68];
  __shared__ int scnt;
  const int blk = blockIdx.x;
  if (blk >= 256) {
    attp_body(blk - 256, threadIdx.x, t + 1, ws + OFF_KV, ws + OFF_Q,
              ws + OFF_PM, ws + OFF_PL, ws + OFF_PACC, smem);
    return;
  }
  const int tid = threadIdx.x;
  const int nt = blk >> 3;
  const int ct = blk & 7;
  float* hs = smem;                         // [64][68]
  float* cts = smem + 64 * 68;              // [64][68]
  const float* h = ws + OFF_H;
  const float* Ct = ws + OFF_CT;
  float* ov = ws + OFF_OV;
  int* cnt = (int*)(ws + OFF_CNT);

#pragma unroll
  for (int p = 0; p < 4; ++p) {
    int e = tid + p * 256;
    int r = e >> 4, kq = e & 15;
    float4 v = *(const float4*)(h + (size_t)(nt * 64 + r) * 64 + kq * 4);
    *(float4*)(hs + r * 68 + kq * 4) = v;
  }
#pragma unroll
  for (int p = 0; p < 4; ++p) {
    int e = tid + p * 256;
    int k = e >> 4, cq = e & 15;
    float4 v = *(const float4*)(Ct + (size_t)k * 512 + ct * 64 + cq * 4);
    *(float4*)(cts + k * 68 + cq * 4) = v;
  }
  if (tid == 0) scnt = 0;
  __syncthreads();

  const int tr = tid >> 4, tc = tid & 15;
  v2f acc[4][2];
#pragma unroll
  for (int i = 0; i < 4; ++i) { acc[i][0] = (v2f){0.f, 0.f}; acc[i][1] = (v2f){0.f, 0.f}; }

#pragma unroll 4
  for (int k4 = 0; k4 < 16; ++k4) {
    float4 hv[4];
#pragma unroll
    for (int i = 0; i < 4; ++i) hv[i] = *(const float4*)(hs + (tr + i * 16) * 68 + k4 * 4);
#pragma unroll
    for (int kk = 0; kk < 4; ++kk) {
      float4 c = *(const float4*)(cts + (k4 * 4 + kk) * 68 + tc * 4);
      v2f c0 = {c.x, c.y}, c1 = {c.z, c.w};
#pragma unroll
      for (int i = 0; i < 4; ++i) {
        float hvv = ((const float*)&hv[i])[kk];
        v2f hvp = {hvv, hvv};
        acc[i][0] = pkfma(hvp, c0, acc[i][0]);
        acc[i][1] = pkfma(hvp, c1, acc[i][1]);
      }
    }
  }

  float thr = thr_o0[0];
  const float inv = 1.0f / 1048576.0f;
  for (int i = 0; i < t; ++i) {
    float mean = (float)cnt[16 + i] * inv;
    thr = fmaxf(thr + 0.1f * (mean - 0.02f), 0.5f);
  }

  int mycount = 0;
#pragma unroll
  for (int i = 0; i < 4; ++i) {
    int n = nt * 64 + tr + i * 16;
    int b = n >> 8, s = n & 255;
    size_t coff = (size_t)ct * 64 + tc * 4;
    float* ovp = ov + (size_t)n * 512 + coff;
    float* outp = out + ((size_t)(b * 16 + t) * 256 + s) * 512 + coff;
    float4 o = *(float4*)ovp;
    float v0 = o.x * MEMDECAY + acc[i][0].x;
    float v1 = o.y * MEMDECAY + acc[i][0].y;
    float v2_ = o.z * MEMDECAY + acc[i][1].x;
    float v3 = o.w * MEMDECAY + acc[i][1].y;
    float s0 = (v0 >= thr) ? 1.f : 0.f;
    float s1 = (v1 >= thr) ? 1.f : 0.f;
    float s2 = (v2_ >= thr) ? 1.f : 0.f;
    float s3 = (v3 >= thr) ? 1.f : 0.f;
    float4 sp; sp.x = s0; sp.y = s1; sp.z = s2; sp.w = s3;
    *(float4*)outp = sp;
    float4 nv; nv.x = v0 * (1.f - s0); nv.y = v1 * (1.f - s1);
    nv.z = v2_ * (1.f - s2); nv.w = v3 * (1.f - s3);
    *(float4*)ovp = nv;
    mycount += (int)(s0 + s1 + s2 + s3);
  }
  atomicAdd(&scnt, mycount);
  __syncthreads();
  if (tid == 0) atomicAdd(&cnt[16 + t], scnt);
}

// ---------------------------------------------------------------------------
extern "C" void kernel_launch(void* const* d_in, const int* in_sizes, int n_in,
                              void* d_out, int out_size, void* d_ws, size_t ws_size,
                              hipStream_t stream) {
  const float* x    = (const float*)d_in[0];
  const float* A    = (const float*)d_in[1];
  const float* C    = (const float*)d_in[2];
  const float* Wq   = (const float*)d_in[3];
  const float* bq   = (const float*)d_in[4];
  const float* Wkv  = (const float*)d_in[5];
  const float* bkv  = (const float*)d_in[6];
  const float* Wo   = (const float*)d_in[7];
  const float* bo   = (const float*)d_in[8];
  const float* th_s = (const float*)d_in[9];
  const float* th_o = (const float*)d_in[10];
  float* out = (float*)d_out;
  float* ws = (float*)d_ws;

  init_kernel<<<dim3(2177), dim3(256), 0, stream>>>(bq, C, Wkv, ws);
  kv_gemm_kernel<<<dim3(512), dim3(256), 0, stream>>>(x, ws + OFF_WT, bkv, ws);
  attp_kernel<<<dim3(256), dim3(256), 0, stream>>>(0, ws);
  for (int t = 0; t < TSTEPS; ++t) {
    combine_lifs_kernel<<<dim3(512), dim3(256), 0, stream>>>(t, A, Wq, bq, Wo, bo, th_s, ws);
    int g = (t < TSTEPS - 1) ? 512 : 256;
    fused_out_attp_kernel<<<dim3(g), dim3(256), 0, stream>>>(t, th_o, out, ws);
  }
}

// Round 4
// 974.196 us; speedup vs baseline: 2.4193x; 1.2269x over previous
//
#include <hip/hip_runtime.h>
#include <math.h>

// ---------------------------------------------------------------------------
// AttentionalSpikingSSMLayer  (B=8, T=16, S=256, D=512, DS=64, H=4, dh=16)
// All compute fp32 (no fp32 MFMA on CDNA4; Heaviside spikes need fp32 margin).
// R1: LIF-O ballot-gather -> dense LDS GEMM (1714 -> 1258 us).
// R2: kv_gemm vectorized LDS; combine gathers -> dense b128 dots. (1002 us)
// R3: NSPLIT 32->16 REGRESSED (1143): attp at 256 blocks = 1 wave/SIMD, no
//     latency hiding. exp2f + b128 LIF-O reads kept (sound).
// R4: cooperative mega-kernel FAILED (2767): grid.sync = per-XCD L2 flush.
// R5: packed fp32 REGRESSED (1195): kv_gemm is LDS-pipe-bound, packing FMA
//     only added VGPR pressure (68->88).
// R6: revert to proven NSPLIT=32 scalar structure + exp2f + b128 LIF-O.
//     NEW: sparse spike dots in combine (wave-uniform ballot mask, ascending-k
//     ctz loop; bit-identical to dense since fma(0,w,s)==s exactly).
// ---------------------------------------------------------------------------

#define NTOK   2048          // B*S
#define TSTEPS 16
#define NSPLIT 32            // key splits for flash partials (64 keys each)

#define MEMDECAY ((float)0.6065306597126334)
#define SCALE    0.25f       // 1/sqrt(dh)
#define LOG2E    1.4426950408889634f

// workspace layout (float offsets)
#define OFF_KV   ((size_t)0)                      // 16*2048*128
#define OFF_PACC ((size_t)4194304)                // 4*32*2048*16
#define OFF_OV   ((size_t)8388608)                // 2048*512
#define OFF_H    ((size_t)9437184)                // 2048*64
#define OFF_SV   ((size_t)9568256)
#define OFF_Q    ((size_t)9699328)
#define OFF_PM   ((size_t)9830400)                // 4*32*2048
#define OFF_PL   ((size_t)10092544)               // 4*32*2048
#define OFF_CT   ((size_t)10354688)               // 64*512 (C transposed)
#define OFF_CNT  ((size_t)10387456)               // 32 ints: [0..15]=s, [16..31]=o
#define OFF_WT   ((size_t)10387488)               // 512*128 (Wkv transposed)

// ---------------------------------------------------------------------------
// init: zero ov+h+sv, q <- bq, C_t transpose, Wkv_t transpose, zero counters.
// ---------------------------------------------------------------------------
__global__ __launch_bounds__(256) void init_kernel(const float* __restrict__ bq,
                                                   const float* __restrict__ C,
                                                   const float* __restrict__ Wkv,
                                                   float* __restrict__ ws) {
  int i = blockIdx.x * 256 + threadIdx.x;
  if (i < 327680) {                       // zero ov+h+sv (float4)
    float4 z = {0.f, 0.f, 0.f, 0.f};
    ((float4*)(ws + OFF_OV))[i] = z;
    return;
  }
  i -= 327680;
  if (i < 131072) { ws[OFF_Q + i] = bq[i & 63]; return; }
  i -= 131072;
  if (i < 32768) {                        // C_t[k][c] = C[c][k]
    int k = i >> 9, c = i & 511;
    ws[OFF_CT + i] = C[c * 64 + k];
    return;
  }
  i -= 32768;
  if (i < 65536) {                        // Wkv_t[k][o] = Wkv[o][k]
    int k = i >> 7, o = i & 127;
    ws[OFF_WT + i] = Wkv[o * 512 + k];
    return;
  }
  i -= 65536;
  if (i < 32) ((int*)(ws + OFF_CNT))[i] = 0;
}

// ---------------------------------------------------------------------------
// KV projection: kv[t][n][o] = sum_d x[row][d]*Wkv[o][d] + bkv[o]
// M=32768 rows, K=512, Nc=128. Block: 64 rows x 128 cols, thread: 4x8.
// (proven scalar version — LDS-pipe-bound, do not touch FMA form)
// ---------------------------------------------------------------------------
__global__ __launch_bounds__(256) void kv_gemm_kernel(const float* __restrict__ x,
                                                      const float* __restrict__ wkt,
                                                      const float* __restrict__ bkv,
                                                      float* __restrict__ ws) {
  __shared__ float xs[64 * 68];        // rows x k, stride 68
  __shared__ float wt[64 * 136];       // k x cols, stride 136
  const int tid = threadIdx.x;
  const int mbase = blockIdx.x * 64;
  const int rg = tid >> 4;             // rows rg*4 .. rg*4+3
  const int cg = tid & 15;             // cols cg*8 .. cg*8+7

  float acc[4][8];
#pragma unroll
  for (int i = 0; i < 4; ++i)
#pragma unroll
    for (int j = 0; j < 8; ++j) acc[i][j] = 0.f;

  for (int kt = 0; kt < 8; ++kt) {
    const int kb = kt * 64;
#pragma unroll
    for (int p = 0; p < 4; ++p) {
      int e = tid + p * 256;
      int r = e >> 4, kq = e & 15;
      int row = mbase + r;
      int t_ = row >> 11, n = row & 2047;
      int b = n >> 8, s = n & 255;
      float4 v = *(const float4*)(x + (size_t)((b * 16 + t_) * 256 + s) * 512 + kb + kq * 4);
      *(float4*)(xs + r * 68 + kq * 4) = v;
    }
#pragma unroll
    for (int p = 0; p < 8; ++p) {
      int e = tid + p * 256;
      int k = e >> 5, cq = e & 31;
      float4 v = *(const float4*)(wkt + (size_t)(kb + k) * 128 + cq * 4);
      *(float4*)(wt + k * 136 + cq * 4) = v;
    }
    __syncthreads();
#pragma unroll 2
    for (int kq = 0; kq < 16; ++kq) {
      float4 a0 = *(const float4*)(xs + (rg * 4 + 0) * 68 + kq * 4);
      float4 a1 = *(const float4*)(xs + (rg * 4 + 1) * 68 + kq * 4);
      float4 a2 = *(const float4*)(xs + (rg * 4 + 2) * 68 + kq * 4);
      float4 a3 = *(const float4*)(xs + (rg * 4 + 3) * 68 + kq * 4);
      const float* ap[4] = {(const float*)&a0, (const float*)&a1,
                            (const float*)&a2, (const float*)&a3};
#pragma unroll
      for (int kk = 0; kk < 4; ++kk) {
        const float* wp = wt + (kq * 4 + kk) * 136 + cg * 8;
        float4 b0 = *(const float4*)(wp);
        float4 b1 = *(const float4*)(wp + 4);
#pragma unroll
        for (int i = 0; i < 4; ++i) {
          float av = ap[i][kk];
          acc[i][0] += av * b0.x; acc[i][1] += av * b0.y;
          acc[i][2] += av * b0.z; acc[i][3] += av * b0.w;
          acc[i][4] += av * b1.x; acc[i][5] += av * b1.y;
          acc[i][6] += av * b1.z; acc[i][7] += av * b1.w;
        }
      }
    }
    __syncthreads();
  }
  float4 bb0 = *(const float4*)(bkv + cg * 8);
  float4 bb1 = *(const float4*)(bkv + cg * 8 + 4);
  float* kvout = ws + OFF_KV;
#pragma unroll
  for (int i = 0; i < 4; ++i) {
    float* op = kvout + (size_t)(mbase + rg * 4 + i) * 128 + cg * 8;
    float4 v0; v0.x = acc[i][0] + bb0.x; v0.y = acc[i][1] + bb0.y;
    v0.z = acc[i][2] + bb0.z; v0.w = acc[i][3] + bb0.w;
    float4 v1; v1.x = acc[i][4] + bb1.x; v1.y = acc[i][5] + bb1.y;
    v1.z = acc[i][6] + bb1.z; v1.w = acc[i][7] + bb1.w;
    *(float4*)(op) = v0;
    *(float4*)(op + 4) = v1;
  }
}

// ---------------------------------------------------------------------------
// attention partials (flash, key-split). blk: head(2b) | qtile(2b) | split(5b)
// 256 thr, 2 queries/thread, 64 keys/block. exp via exp2f on reduced args.
// ---------------------------------------------------------------------------
__device__ __forceinline__ void attp_body(int blk, int tid, int t,
                                          const float* __restrict__ kvbase,
                                          const float* __restrict__ qbuf,
                                          float* __restrict__ pm,
                                          float* __restrict__ pl,
                                          float* __restrict__ pacc,
                                          float* smem) {
  const int head = blk & 3;
  const int qt = (blk >> 2) & 3;
  const int sp = blk >> 4;                 // 0..31
  float* kl = smem;                        // [64][16]
  float* vl = smem + 1024;
  const float* kvt = kvbase + (size_t)t * NTOK * 128;
  {
    int key = tid >> 2, dq = tid & 3;
    const float* base = kvt + (size_t)(sp * 64 + key) * 128 + head * 16;
    float4 kk = ((const float4*)base)[dq];
    float4 vv = ((const float4*)(base + 64))[dq];
    ((float4*)kl)[key * 4 + dq] = kk;
    ((float4*)vl)[key * 4 + dq] = vv;
  }
  const int i0 = qt * 512 + tid;
  const int i1 = i0 + 256;
  float q0[16], q1[16];
  {
    const float4* qp0 = (const float4*)(qbuf + (size_t)i0 * 64 + head * 16);
    const float4* qp1 = (const float4*)(qbuf + (size_t)i1 * 64 + head * 16);
#pragma unroll
    for (int r = 0; r < 4; ++r) {
      float4 a = qp0[r];
      q0[4 * r] = a.x; q0[4 * r + 1] = a.y; q0[4 * r + 2] = a.z; q0[4 * r + 3] = a.w;
      float4 b = qp1[r];
      q1[4 * r] = b.x; q1[4 * r + 1] = b.y; q1[4 * r + 2] = b.z; q1[4 * r + 3] = b.w;
    }
  }
  __syncthreads();
  float m0 = -INFINITY, l0 = 0.f, m1 = -INFINITY, l1 = 0.f;
  float acc0[16], acc1[16];
#pragma unroll
  for (int d = 0; d < 16; ++d) { acc0[d] = 0.f; acc1[d] = 0.f; }

#pragma unroll
  for (int ch = 0; ch < 4; ++ch) {         // 16-key chunks
    float sc0[16], sc1[16];
#pragma unroll
    for (int j = 0; j < 16; ++j) {
      const float* kp = kl + (ch * 16 + j) * 16;
      float s0 = 0.f, s1 = 0.f;
#pragma unroll
      for (int d = 0; d < 16; ++d) { float kv_ = kp[d]; s0 += q0[d] * kv_; s1 += q1[d] * kv_; }
      sc0[j] = s0 * SCALE; sc1[j] = s1 * SCALE;
    }
    float mb0 = sc0[0], mb1 = sc1[0];
#pragma unroll
    for (int j = 1; j < 16; ++j) { mb0 = fmaxf(mb0, sc0[j]); mb1 = fmaxf(mb1, sc1[j]); }
    float mn0 = fmaxf(m0, mb0), mn1 = fmaxf(m1, mb1);
    float r0 = exp2f((m0 - mn0) * LOG2E), r1 = exp2f((m1 - mn1) * LOG2E);
    l0 *= r0; l1 *= r1;
#pragma unroll
    for (int d = 0; d < 16; ++d) { acc0[d] *= r0; acc1[d] *= r1; }
#pragma unroll
    for (int j = 0; j < 16; ++j) {
      float w0 = exp2f((sc0[j] - mn0) * LOG2E), w1 = exp2f((sc1[j] - mn1) * LOG2E);
      l0 += w0; l1 += w1; sc0[j] = w0; sc1[j] = w1;
    }
#pragma unroll
    for (int j = 0; j < 16; ++j) {
      const float* vp = vl + (ch * 16 + j) * 16;
      float w0 = sc0[j], w1 = sc1[j];
#pragma unroll
      for (int d = 0; d < 16; ++d) { float vv = vp[d]; acc0[d] += w0 * vv; acc1[d] += w1 * vv; }
    }
    m0 = mn0; m1 = mn1;
  }
  const int pbase = (head * NSPLIT + sp) * NTOK;
  pm[pbase + i0] = m0; pm[pbase + i1] = m1;
  pl[pbase + i0] = l0; pl[pbase + i1] = l1;
  float4* pa0 = (float4*)(pacc + (size_t)(pbase + i0) * 16);
  float4* pa1 = (float4*)(pacc + (size_t)(pbase + i1) * 16);
#pragma unroll
  for (int r = 0; r < 4; ++r) {
    float4 v0; v0.x = acc0[4 * r]; v0.y = acc0[4 * r + 1]; v0.z = acc0[4 * r + 2]; v0.w = acc0[4 * r + 3];
    pa0[r] = v0;
    float4 v1; v1.x = acc1[4 * r]; v1.y = acc1[4 * r + 1]; v1.z = acc1[4 * r + 2]; v1.w = acc1[4 * r + 3];
    pa1[r] = v1;
  }
}

__global__ __launch_bounds__(256) void attp_kernel(int t, float* __restrict__ ws) {
  __shared__ float smem[2048];
  attp_body(blockIdx.x, threadIdx.x, t, ws + OFF_KV, ws + OFF_Q,
            ws + OFF_PM, ws + OFF_PL, ws + OFF_PACC, smem);
}

// ---------------------------------------------------------------------------
// combine partials -> att ; su = h@A.T + att@Wo.T + bo ; LIF-S; q(t+1).
// One wave per token. h and spk dots use wave-uniform sparse ballot masks
// (ascending-k ctz loop; bit-identical to dense: fma(0,w,s)==s exactly).
// ---------------------------------------------------------------------------
__global__ __launch_bounds__(256) void combine_lifs_kernel(
    int t, const float* __restrict__ A, const float* __restrict__ Wq,
    const float* __restrict__ bq, const float* __restrict__ Wo,
    const float* __restrict__ bo, const float* __restrict__ thr_s0,
    float* __restrict__ ws) {
  __shared__ float As[64 * 68], Wqs[64 * 68], Wos[64 * 68];  // row-major, c x k
  __shared__ float att_s[4][64];
  __shared__ int scnt;
  const int tid = threadIdx.x;
#pragma unroll
  for (int p = 0; p < 4; ++p) {
    int e = tid + p * 256;
    int c = e >> 4, kq = e & 15;
    *(float4*)(As + c * 68 + kq * 4)  = *(const float4*)(A + c * 64 + kq * 4);
    *(float4*)(Wqs + c * 68 + kq * 4) = *(const float4*)(Wq + c * 64 + kq * 4);
    *(float4*)(Wos + c * 68 + kq * 4) = *(const float4*)(Wo + c * 64 + kq * 4);
  }
  if (tid == 0) scnt = 0;

  const float* pm = ws + OFF_PM;
  const float* pl = ws + OFF_PL;
  const float* pacc = ws + OFF_PACC;
  float* h = ws + OFF_H;
  float* sv = ws + OFF_SV;
  float* qb = ws + OFF_Q;
  int* cnt = (int*)(ws + OFF_CNT);

  const int lane = tid & 63, w = tid >> 6;
  const int n = blockIdx.x * 4 + w;
  const int head = lane >> 4, d = lane & 15;
  const int pb = head * NSPLIT * NTOK + n;

  float mstar = -INFINITY;
  for (int s = 0; s < NSPLIT; ++s) mstar = fmaxf(mstar, pm[pb + s * NTOK]);
  float lst = 0.f, av = 0.f;
  for (int s = 0; s < NSPLIT; ++s) {
    float e = exp2f((pm[pb + s * NTOK] - mstar) * LOG2E);
    lst += e * pl[pb + s * NTOK];
    av += e * pacc[(size_t)(pb + s * NTOK) * 16 + d];
  }
  att_s[w][lane] = av / lst;
  float hv = h[n * 64 + lane];
  unsigned long long hm = __ballot(hv > 0.5f);   // wave-uniform spike mask
  __syncthreads();

  // sparse st = sum_{k in hm} A[lane][k]  (ascending k; == dense fma chain)
  float st = 0.f;
  {
    unsigned long long m = hm;
    while (m) {
      int k = __builtin_ctzll(m);
      m &= m - 1;
      st += As[lane * 68 + k];
    }
  }
  // dense wo = sum_k att[k]*Wo[lane][k]
  const float* Wor = Wos + lane * 68;
  float wo = 0.f;
#pragma unroll
  for (int kq = 0; kq < 16; ++kq) {
    float4 wb = *(const float4*)(Wor + kq * 4);
    float4 ab = *(const float4*)(&att_s[w][kq * 4]);
    wo += ab.x * wb.x; wo += ab.y * wb.y; wo += ab.z * wb.z; wo += ab.w * wb.w;
  }
  float su = st + wo + bo[lane];

  float thr = thr_s0[0];
  const float inv = 1.0f / 131072.0f;      // 2048*64 (power of 2 -> exact)
  for (int i = 0; i < t; ++i) {
    float mean = (float)cnt[i] * inv;
    thr = fmaxf(thr + 0.1f * (mean - 0.02f), 0.5f);
  }
  float svo = sv[n * 64 + lane];
  float vpot = svo * MEMDECAY + su;
  float spk = (vpot >= thr) ? 1.f : 0.f;
  h[n * 64 + lane] = spk;
  sv[n * 64 + lane] = vpot * (1.f - spk);
  unsigned long long sm = __ballot(spk > 0.5f);  // wave-uniform

  // sparse q = sum_{k in sm} Wq[lane][k] + bq[lane]
  float qv = 0.f;
  {
    unsigned long long m = sm;
    while (m) {
      int k = __builtin_ctzll(m);
      m &= m - 1;
      qv += Wqs[lane * 68 + k];
    }
  }
  qb[n * 64 + lane] = qv + bq[lane];

  if (lane == 0) atomicAdd(&scnt, __popcll(sm));
  __syncthreads();
  if (tid == 0) atomicAdd(&cnt[t], scnt);
}

// ---------------------------------------------------------------------------
// LIF-O: out_pot = h2 @ C.T with fused LIF epilogue; fused with attp(t+1)
// in blocks [256, 768).
// ---------------------------------------------------------------------------
__global__ __launch_bounds__(256) void fused_out_attp_kernel(
    int t, const float* __restrict__ thr_o0, float* __restrict__ out,
    float* __restrict__ ws) {
  __shared__ float smem[64 * 68 + 64 * 68];   // hs [64][68] | cts [64][68]
  __shared__ int scnt;
  const int blk = blockIdx.x;
  if (blk >= 256) {
    attp_body(blk - 256, threadIdx.x, t + 1, ws + OFF_KV, ws + OFF_Q,
              ws + OFF_PM, ws + OFF_PL, ws + OFF_PACC, smem);
    return;
  }
  const int tid = threadIdx.x;
  const int nt = blk >> 3;                  // token tile 0..31
  const int ct = blk & 7;                   // channel tile 0..7
  float* hs = smem;                         // [64][68]
  float* cts = smem + 64 * 68;              // [64][68]
  const float* h = ws + OFF_H;
  const float* Ct = ws + OFF_CT;
  float* ov = ws + OFF_OV;
  int* cnt = (int*)(ws + OFF_CNT);

#pragma unroll
  for (int p = 0; p < 4; ++p) {
    int e = tid + p * 256;
    int r = e >> 4, kq = e & 15;
    float4 v = *(const float4*)(h + (size_t)(nt * 64 + r) * 64 + kq * 4);
    *(float4*)(hs + r * 68 + kq * 4) = v;
  }
#pragma unroll
  for (int p = 0; p < 4; ++p) {
    int e = tid + p * 256;
    int k = e >> 4, cq = e & 15;
    float4 v = *(const float4*)(Ct + (size_t)k * 512 + ct * 64 + cq * 4);
    *(float4*)(cts + k * 68 + cq * 4) = v;
  }
  if (tid == 0) scnt = 0;
  __syncthreads();

  const int tr = tid >> 4, tc = tid & 15;   // rows tr+i*16, cols tc*4+j
  float acc[4][4];
#pragma unroll
  for (int i = 0; i < 4; ++i)
#pragma unroll
    for (int j = 0; j < 4; ++j) acc[i][j] = 0.f;

#pragma unroll 4
  for (int k4 = 0; k4 < 16; ++k4) {         // 4 k-values per iter, b128 reads
    float4 hv[4];
#pragma unroll
    for (int i = 0; i < 4; ++i) hv[i] = *(const float4*)(hs + (tr + i * 16) * 68 + k4 * 4);
#pragma unroll
    for (int kk = 0; kk < 4; ++kk) {
      float4 c = *(const float4*)(cts + (k4 * 4 + kk) * 68 + tc * 4);
#pragma unroll
      for (int i = 0; i < 4; ++i) {
        float hvv = ((const float*)&hv[i])[kk];
        acc[i][0] += hvv * c.x;
        acc[i][1] += hvv * c.y;
        acc[i][2] += hvv * c.z;
        acc[i][3] += hvv * c.w;
      }
    }
  }

  float thr = thr_o0[0];
  const float inv = 1.0f / 1048576.0f;      // 2048*512
  for (int i = 0; i < t; ++i) {
    float mean = (float)cnt[16 + i] * inv;
    thr = fmaxf(thr + 0.1f * (mean - 0.02f), 0.5f);
  }

  int mycount = 0;
#pragma unroll
  for (int i = 0; i < 4; ++i) {
    int n = nt * 64 + tr + i * 16;
    int b = n >> 8, s = n & 255;
    size_t coff = (size_t)ct * 64 + tc * 4;
    float* ovp = ov + (size_t)n * 512 + coff;
    float* outp = out + ((size_t)(b * 16 + t) * 256 + s) * 512 + coff;
    float4 o = *(float4*)ovp;
    float v0 = o.x * MEMDECAY + acc[i][0];
    float v1 = o.y * MEMDECAY + acc[i][1];
    float v2 = o.z * MEMDECAY + acc[i][2];
    float v3 = o.w * MEMDECAY + acc[i][3];
    float s0 = (v0 >= thr) ? 1.f : 0.f;
    float s1 = (v1 >= thr) ? 1.f : 0.f;
    float s2 = (v2 >= thr) ? 1.f : 0.f;
    float s3 = (v3 >= thr) ? 1.f : 0.f;
    float4 sp; sp.x = s0; sp.y = s1; sp.z = s2; sp.w = s3;
    *(float4*)outp = sp;
    float4 nv; nv.x = v0 * (1.f - s0); nv.y = v1 * (1.f - s1);
    nv.z = v2 * (1.f - s2); nv.w = v3 * (1.f - s3);
    *(float4*)ovp = nv;
    mycount += (int)(s0 + s1 + s2 + s3);
  }
  atomicAdd(&scnt, mycount);
  __syncthreads();
  if (tid == 0) atomicAdd(&cnt[16 + t], scnt);
}

// ---------------------------------------------------------------------------
extern "C" void kernel_launch(void* const* d_in, const int* in_sizes, int n_in,
                              void* d_out, int out_size, void* d_ws, size_t ws_size,
                              hipStream_t stream) {
  const float* x    = (const float*)d_in[0];
  const float* A    = (const float*)d_in[1];
  const float* C    = (const float*)d_in[2];
  const float* Wq   = (const float*)d_in[3];
  const float* bq   = (const float*)d_in[4];
  const float* Wkv  = (const float*)d_in[5];
  const float* bkv  = (const float*)d_in[6];
  const float* Wo   = (const float*)d_in[7];
  const float* bo   = (const float*)d_in[8];
  const float* th_s = (const float*)d_in[9];
  const float* th_o = (const float*)d_in[10];
  float* out = (float*)d_out;
  float* ws = (float*)d_ws;

  init_kernel<<<dim3(2177), dim3(256), 0, stream>>>(bq, C, Wkv, ws);
  kv_gemm_kernel<<<dim3(512), dim3(256), 0, stream>>>(x, ws + OFF_WT, bkv, ws);
  attp_kernel<<<dim3(512), dim3(256), 0, stream>>>(0, ws);
  for (int t = 0; t < TSTEPS; ++t) {
    combine_lifs_kernel<<<dim3(512), dim3(256), 0, stream>>>(t, A, Wq, bq, Wo, bo, th_s, ws);
    int g = (t < TSTEPS - 1) ? 768 : 256;
    fused_out_attp_kernel<<<dim3(g), dim3(256), 0, stream>>>(t, th_o, out, ws);
  }
}

// Round 5
// 910.252 us; speedup vs baseline: 2.5892x; 1.0702x over previous
//
#include <hip/hip_runtime.h>
#include <math.h>

// ---------------------------------------------------------------------------
// AttentionalSpikingSSMLayer  (B=8, T=16, S=256, D=512, DS=64, H=4, dh=16)
// All compute fp32 (no fp32 MFMA on CDNA4; Heaviside spikes need fp32 margin).
// R1: LIF-O ballot-gather -> dense LDS GEMM (1714 -> 1258 us).
// R2: kv_gemm vectorized LDS; combine gathers -> dense b128 dots. (1002 us)
// R3: NSPLIT 32->16 REGRESSED (1143): attp at 256 blocks = 1 wave/SIMD.
// R4: cooperative mega-kernel FAILED (2767): grid.sync = per-XCD L2 flush.
// R5: packed fp32 REGRESSED (1195): kv_gemm is LDS-pipe-bound.
// R6: NSPLIT=32 + exp2f + sparse ballot dots in combine. (974 us)
// R7: kv_gemm B-read 4-way bank conflict fix (cols cg*4 & 64+cg*4: 16B-stride
//     addrs -> 2-way = free; bit-identical, only thread->col map changes).
//     LIF-O GEMM -> sparse hmask gather straight from global C_t (h2 ~2%
//     density; ascending-k adds == dense fma chain exactly). h array dropped;
//     combine reads/writes 64b spike masks. Fused kernel LDS 34.8KB -> 8KB.
// ---------------------------------------------------------------------------

#define NTOK   2048          // B*S
#define TSTEPS 16
#define NSPLIT 32            // key splits for flash partials (64 keys each)

#define MEMDECAY ((float)0.6065306597126334)
#define SCALE    0.25f       // 1/sqrt(dh)
#define LOG2E    1.4426950408889634f

// workspace layout (float offsets)
#define OFF_KV   ((size_t)0)                      // 16*2048*128
#define OFF_PACC ((size_t)4194304)                // 4*32*2048*16
#define OFF_OV   ((size_t)8388608)                // 2048*512
#define OFF_H    ((size_t)9437184)                // (unused since R7)
#define OFF_SV   ((size_t)9568256)
#define OFF_Q    ((size_t)9699328)
#define OFF_PM   ((size_t)9830400)                // 4*32*2048
#define OFF_PL   ((size_t)10092544)               // 4*32*2048
#define OFF_CT   ((size_t)10354688)               // 64*512 (C transposed)
#define OFF_CNT  ((size_t)10387456)               // 32 ints: [0..15]=s, [16..31]=o
#define OFF_WT   ((size_t)10387488)               // 512*128 (Wkv transposed)
#define OFF_HM   ((size_t)10453024)               // 2048 uint64 spike masks

// ---------------------------------------------------------------------------
// init: zero ov+h+sv, q <- bq, C_t transpose, Wkv_t transpose, zero counters,
// zero spike masks.
// ---------------------------------------------------------------------------
__global__ __launch_bounds__(256) void init_kernel(const float* __restrict__ bq,
                                                   const float* __restrict__ C,
                                                   const float* __restrict__ Wkv,
                                                   float* __restrict__ ws) {
  int i = blockIdx.x * 256 + threadIdx.x;
  if (i < 327680) {                       // zero ov+h+sv (float4)
    float4 z = {0.f, 0.f, 0.f, 0.f};
    ((float4*)(ws + OFF_OV))[i] = z;
    return;
  }
  i -= 327680;
  if (i < 131072) { ws[OFF_Q + i] = bq[i & 63]; return; }
  i -= 131072;
  if (i < 32768) {                        // C_t[k][c] = C[c][k]
    int k = i >> 9, c = i & 511;
    ws[OFF_CT + i] = C[c * 64 + k];
    return;
  }
  i -= 32768;
  if (i < 65536) {                        // Wkv_t[k][o] = Wkv[o][k]
    int k = i >> 7, o = i & 127;
    ws[OFF_WT + i] = Wkv[o * 512 + k];
    return;
  }
  i -= 65536;
  if (i < 32) { ((int*)(ws + OFF_CNT))[i] = 0; return; }
  i -= 32;
  if (i < 1024) {                         // zero hmask (1024 float4 = 4096 f)
    float4 z = {0.f, 0.f, 0.f, 0.f};
    ((float4*)(ws + OFF_HM))[i] = z;
  }
}

// ---------------------------------------------------------------------------
// KV projection: kv[t][n][o] = sum_d x[row][d]*Wkv[o][d] + bkv[o]
// M=32768 rows, K=512, Nc=128. Block: 64 rows x 128 cols, thread: 4 rows x
// cols {cg*4..+3, 64+cg*4..+3} (16B-stride B reads: bank-conflict-free).
// ---------------------------------------------------------------------------
__global__ __launch_bounds__(256) void kv_gemm_kernel(const float* __restrict__ x,
                                                      const float* __restrict__ wkt,
                                                      const float* __restrict__ bkv,
                                                      float* __restrict__ ws) {
  __shared__ float xs[64 * 68];        // rows x k, stride 68
  __shared__ float wt[64 * 136];       // k x cols, stride 136
  const int tid = threadIdx.x;
  const int mbase = blockIdx.x * 64;
  const int rg = tid >> 4;             // rows rg*4 .. rg*4+3
  const int cg = tid & 15;             // cols cg*4..cg*4+3 and 64+cg*4..+3

  float acc[4][8];
#pragma unroll
  for (int i = 0; i < 4; ++i)
#pragma unroll
    for (int j = 0; j < 8; ++j) acc[i][j] = 0.f;

  for (int kt = 0; kt < 8; ++kt) {
    const int kb = kt * 64;
#pragma unroll
    for (int p = 0; p < 4; ++p) {
      int e = tid + p * 256;
      int r = e >> 4, kq = e & 15;
      int row = mbase + r;
      int t_ = row >> 11, n = row & 2047;
      int b = n >> 8, s = n & 255;
      float4 v = *(const float4*)(x + (size_t)((b * 16 + t_) * 256 + s) * 512 + kb + kq * 4);
      *(float4*)(xs + r * 68 + kq * 4) = v;
    }
#pragma unroll
    for (int p = 0; p < 8; ++p) {
      int e = tid + p * 256;
      int k = e >> 5, cq = e & 31;
      float4 v = *(const float4*)(wkt + (size_t)(kb + k) * 128 + cq * 4);
      *(float4*)(wt + k * 136 + cq * 4) = v;
    }
    __syncthreads();
#pragma unroll 2
    for (int kq = 0; kq < 16; ++kq) {
      float4 a0 = *(const float4*)(xs + (rg * 4 + 0) * 68 + kq * 4);
      float4 a1 = *(const float4*)(xs + (rg * 4 + 1) * 68 + kq * 4);
      float4 a2 = *(const float4*)(xs + (rg * 4 + 2) * 68 + kq * 4);
      float4 a3 = *(const float4*)(xs + (rg * 4 + 3) * 68 + kq * 4);
      const float* ap[4] = {(const float*)&a0, (const float*)&a1,
                            (const float*)&a2, (const float*)&a3};
#pragma unroll
      for (int kk = 0; kk < 4; ++kk) {
        const float* wp = wt + (kq * 4 + kk) * 136;
        float4 b0 = *(const float4*)(wp + cg * 4);        // 16B stride: free
        float4 b1 = *(const float4*)(wp + 64 + cg * 4);   // 16B stride: free
#pragma unroll
        for (int i = 0; i < 4; ++i) {
          float av = ap[i][kk];
          acc[i][0] += av * b0.x; acc[i][1] += av * b0.y;
          acc[i][2] += av * b0.z; acc[i][3] += av * b0.w;
          acc[i][4] += av * b1.x; acc[i][5] += av * b1.y;
          acc[i][6] += av * b1.z; acc[i][7] += av * b1.w;
        }
      }
    }
    __syncthreads();
  }
  float4 bb0 = *(const float4*)(bkv + cg * 4);
  float4 bb1 = *(const float4*)(bkv + 64 + cg * 4);
  float* kvout = ws + OFF_KV;
#pragma unroll
  for (int i = 0; i < 4; ++i) {
    float* op = kvout + (size_t)(mbase + rg * 4 + i) * 128;
    float4 v0; v0.x = acc[i][0] + bb0.x; v0.y = acc[i][1] + bb0.y;
    v0.z = acc[i][2] + bb0.z; v0.w = acc[i][3] + bb0.w;
    float4 v1; v1.x = acc[i][4] + bb1.x; v1.y = acc[i][5] + bb1.y;
    v1.z = acc[i][6] + bb1.z; v1.w = acc[i][7] + bb1.w;
    *(float4*)(op + cg * 4) = v0;
    *(float4*)(op + 64 + cg * 4) = v1;
  }
}

// ---------------------------------------------------------------------------
// attention partials (flash, key-split). blk: head(2b) | qtile(2b) | split(5b)
// 256 thr, 2 queries/thread, 64 keys/block. exp via exp2f on reduced args.
// ---------------------------------------------------------------------------
__device__ __forceinline__ void attp_body(int blk, int tid, int t,
                                          const float* __restrict__ kvbase,
                                          const float* __restrict__ qbuf,
                                          float* __restrict__ pm,
                                          float* __restrict__ pl,
                                          float* __restrict__ pacc,
                                          float* smem) {
  const int head = blk & 3;
  const int qt = (blk >> 2) & 3;
  const int sp = blk >> 4;                 // 0..31
  float* kl = smem;                        // [64][16]
  float* vl = smem + 1024;
  const float* kvt = kvbase + (size_t)t * NTOK * 128;
  {
    int key = tid >> 2, dq = tid & 3;
    const float* base = kvt + (size_t)(sp * 64 + key) * 128 + head * 16;
    float4 kk = ((const float4*)base)[dq];
    float4 vv = ((const float4*)(base + 64))[dq];
    ((float4*)kl)[key * 4 + dq] = kk;
    ((float4*)vl)[key * 4 + dq] = vv;
  }
  const int i0 = qt * 512 + tid;
  const int i1 = i0 + 256;
  float q0[16], q1[16];
  {
    const float4* qp0 = (const float4*)(qbuf + (size_t)i0 * 64 + head * 16);
    const float4* qp1 = (const float4*)(qbuf + (size_t)i1 * 64 + head * 16);
#pragma unroll
    for (int r = 0; r < 4; ++r) {
      float4 a = qp0[r];
      q0[4 * r] = a.x; q0[4 * r + 1] = a.y; q0[4 * r + 2] = a.z; q0[4 * r + 3] = a.w;
      float4 b = qp1[r];
      q1[4 * r] = b.x; q1[4 * r + 1] = b.y; q1[4 * r + 2] = b.z; q1[4 * r + 3] = b.w;
    }
  }
  __syncthreads();
  float m0 = -INFINITY, l0 = 0.f, m1 = -INFINITY, l1 = 0.f;
  float acc0[16], acc1[16];
#pragma unroll
  for (int d = 0; d < 16; ++d) { acc0[d] = 0.f; acc1[d] = 0.f; }

#pragma unroll
  for (int ch = 0; ch < 4; ++ch) {         // 16-key chunks
    float sc0[16], sc1[16];
#pragma unroll
    for (int j = 0; j < 16; ++j) {
      const float* kp = kl + (ch * 16 + j) * 16;
      float s0 = 0.f, s1 = 0.f;
#pragma unroll
      for (int d = 0; d < 16; ++d) { float kv_ = kp[d]; s0 += q0[d] * kv_; s1 += q1[d] * kv_; }
      sc0[j] = s0 * SCALE; sc1[j] = s1 * SCALE;
    }
    float mb0 = sc0[0], mb1 = sc1[0];
#pragma unroll
    for (int j = 1; j < 16; ++j) { mb0 = fmaxf(mb0, sc0[j]); mb1 = fmaxf(mb1, sc1[j]); }
    float mn0 = fmaxf(m0, mb0), mn1 = fmaxf(m1, mb1);
    float r0 = exp2f((m0 - mn0) * LOG2E), r1 = exp2f((m1 - mn1) * LOG2E);
    l0 *= r0; l1 *= r1;
#pragma unroll
    for (int d = 0; d < 16; ++d) { acc0[d] *= r0; acc1[d] *= r1; }
#pragma unroll
    for (int j = 0; j < 16; ++j) {
      float w0 = exp2f((sc0[j] - mn0) * LOG2E), w1 = exp2f((sc1[j] - mn1) * LOG2E);
      l0 += w0; l1 += w1; sc0[j] = w0; sc1[j] = w1;
    }
#pragma unroll
    for (int j = 0; j < 16; ++j) {
      const float* vp = vl + (ch * 16 + j) * 16;
      float w0 = sc0[j], w1 = sc1[j];
#pragma unroll
      for (int d = 0; d < 16; ++d) { float vv = vp[d]; acc0[d] += w0 * vv; acc1[d] += w1 * vv; }
    }
    m0 = mn0; m1 = mn1;
  }
  const int pbase = (head * NSPLIT + sp) * NTOK;
  pm[pbase + i0] = m0; pm[pbase + i1] = m1;
  pl[pbase + i0] = l0; pl[pbase + i1] = l1;
  float4* pa0 = (float4*)(pacc + (size_t)(pbase + i0) * 16);
  float4* pa1 = (float4*)(pacc + (size_t)(pbase + i1) * 16);
#pragma unroll
  for (int r = 0; r < 4; ++r) {
    float4 v0; v0.x = acc0[4 * r]; v0.y = acc0[4 * r + 1]; v0.z = acc0[4 * r + 2]; v0.w = acc0[4 * r + 3];
    pa0[r] = v0;
    float4 v1; v1.x = acc1[4 * r]; v1.y = acc1[4 * r + 1]; v1.z = acc1[4 * r + 2]; v1.w = acc1[4 * r + 3];
    pa1[r] = v1;
  }
}

__global__ __launch_bounds__(256) void attp_kernel(int t, float* __restrict__ ws) {
  __shared__ float smem[2048];
  attp_body(blockIdx.x, threadIdx.x, t, ws + OFF_KV, ws + OFF_Q,
            ws + OFF_PM, ws + OFF_PL, ws + OFF_PACC, smem);
}

// ---------------------------------------------------------------------------
// combine partials -> att ; su = h@A.T + att@Wo.T + bo ; LIF-S; q(t+1).
// One wave per token. Spike state lives as 64-bit masks (OFF_HM): read the
// previous mask, write the new one. Sparse sums ascending-k == dense chain.
// ---------------------------------------------------------------------------
__global__ __launch_bounds__(256) void combine_lifs_kernel(
    int t, const float* __restrict__ A, const float* __restrict__ Wq,
    const float* __restrict__ bq, const float* __restrict__ Wo,
    const float* __restrict__ bo, const float* __restrict__ thr_s0,
    float* __restrict__ ws) {
  __shared__ float As[64 * 68], Wqs[64 * 68], Wos[64 * 68];  // row-major, c x k
  __shared__ float att_s[4][64];
  __shared__ int scnt;
  const int tid = threadIdx.x;
#pragma unroll
  for (int p = 0; p < 4; ++p) {
    int e = tid + p * 256;
    int c = e >> 4, kq = e & 15;
    *(float4*)(As + c * 68 + kq * 4)  = *(const float4*)(A + c * 64 + kq * 4);
    *(float4*)(Wqs + c * 68 + kq * 4) = *(const float4*)(Wq + c * 64 + kq * 4);
    *(float4*)(Wos + c * 68 + kq * 4) = *(const float4*)(Wo + c * 64 + kq * 4);
  }
  if (tid == 0) scnt = 0;

  const float* pm = ws + OFF_PM;
  const float* pl = ws + OFF_PL;
  const float* pacc = ws + OFF_PACC;
  float* sv = ws + OFF_SV;
  float* qb = ws + OFF_Q;
  int* cnt = (int*)(ws + OFF_CNT);
  unsigned long long* hmask = (unsigned long long*)(ws + OFF_HM);

  const int lane = tid & 63, w = tid >> 6;
  const int n = blockIdx.x * 4 + w;
  const int head = lane >> 4, d = lane & 15;
  const int pb = head * NSPLIT * NTOK + n;

  float mstar = -INFINITY;
  for (int s = 0; s < NSPLIT; ++s) mstar = fmaxf(mstar, pm[pb + s * NTOK]);
  float lst = 0.f, av = 0.f;
  for (int s = 0; s < NSPLIT; ++s) {
    float e = exp2f((pm[pb + s * NTOK] - mstar) * LOG2E);
    lst += e * pl[pb + s * NTOK];
    av += e * pacc[(size_t)(pb + s * NTOK) * 16 + d];
  }
  att_s[w][lane] = av / lst;
  unsigned long long hm = hmask[n];        // previous spike mask, wave-uniform
  __syncthreads();

  // sparse st = sum_{k in hm} A[lane][k]  (ascending k; == dense fma chain)
  float st = 0.f;
  {
    unsigned long long m = hm;
    while (m) {
      int k = __builtin_ctzll(m);
      m &= m - 1;
      st += As[lane * 68 + k];
    }
  }
  // dense wo = sum_k att[k]*Wo[lane][k]
  const float* Wor = Wos + lane * 68;
  float wo = 0.f;
#pragma unroll
  for (int kq = 0; kq < 16; ++kq) {
    float4 wb = *(const float4*)(Wor + kq * 4);
    float4 ab = *(const float4*)(&att_s[w][kq * 4]);
    wo += ab.x * wb.x; wo += ab.y * wb.y; wo += ab.z * wb.z; wo += ab.w * wb.w;
  }
  float su = st + wo + bo[lane];

  float thr = thr_s0[0];
  const float inv = 1.0f / 131072.0f;      // 2048*64 (power of 2 -> exact)
  for (int i = 0; i < t; ++i) {
    float mean = (float)cnt[i] * inv;
    thr = fmaxf(thr + 0.1f * (mean - 0.02f), 0.5f);
  }
  float svo = sv[n * 64 + lane];
  float vpot = svo * MEMDECAY + su;
  float spk = (vpot >= thr) ? 1.f : 0.f;
  sv[n * 64 + lane] = vpot * (1.f - spk);
  unsigned long long sm = __ballot(spk > 0.5f);  // wave-uniform

  // sparse q = sum_{k in sm} Wq[lane][k] + bq[lane]
  float qv = 0.f;
  {
    unsigned long long m = sm;
    while (m) {
      int k = __builtin_ctzll(m);
      m &= m - 1;
      qv += Wqs[lane * 68 + k];
    }
  }
  qb[n * 64 + lane] = qv + bq[lane];

  if (lane == 0) {
    hmask[n] = sm;
    atomicAdd(&scnt, __popcll(sm));
  }
  __syncthreads();
  if (tid == 0) atomicAdd(&cnt[t], scnt);
}

// ---------------------------------------------------------------------------
// LIF-O sparse: out_pot[n][c] = sum_{k in hmask[n]} C_t[k][c]; fused LIF
// epilogue. No LDS, no staging: C_t is 128KB L2-resident. Fused with
// attp(t+1) in blocks [256, 768).
// ---------------------------------------------------------------------------
__global__ __launch_bounds__(256) void fused_out_attp_kernel(
    int t, const float* __restrict__ thr_o0, float* __restrict__ out,
    float* __restrict__ ws) {
  __shared__ float smem[2048];              // attp kl|vl only
  __shared__ int scnt;
  const int blk = blockIdx.x;
  if (blk >= 256) {
    attp_body(blk - 256, threadIdx.x, t + 1, ws + OFF_KV, ws + OFF_Q,
              ws + OFF_PM, ws + OFF_PL, ws + OFF_PACC, smem);
    return;
  }
  const int tid = threadIdx.x;
  const int nt = blk >> 3;                  // token tile 0..31
  const int ct = blk & 7;                   // channel tile 0..7
  const float* Ct = ws + OFF_CT;
  float* ov = ws + OFF_OV;
  int* cnt = (int*)(ws + OFF_CNT);
  const unsigned long long* hmask = (const unsigned long long*)(ws + OFF_HM);

  if (tid == 0) scnt = 0;
  __syncthreads();

  const int tr = tid >> 4, tc = tid & 15;   // rows tr+i*16, cols tc*4+j
  float thr = thr_o0[0];
  const float inv = 1.0f / 1048576.0f;      // 2048*512
  for (int i = 0; i < t; ++i) {
    float mean = (float)cnt[16 + i] * inv;
    thr = fmaxf(thr + 0.1f * (mean - 0.02f), 0.5f);
  }

  int mycount = 0;
#pragma unroll
  for (int i = 0; i < 4; ++i) {
    int n = nt * 64 + tr + i * 16;
    size_t coff = (size_t)ct * 64 + tc * 4;
    // sparse gather: ascending-k adds == dense fma chain (h in {0,1})
    float a0 = 0.f, a1 = 0.f, a2 = 0.f, a3 = 0.f;
    unsigned long long m = hmask[n];
    while (m) {
      int k = __builtin_ctzll(m);
      m &= m - 1;
      float4 c = *(const float4*)(Ct + (size_t)k * 512 + coff);
      a0 += c.x; a1 += c.y; a2 += c.z; a3 += c.w;
    }
    int b = n >> 8, s = n & 255;
    float* ovp = ov + (size_t)n * 512 + coff;
    float* outp = out + ((size_t)(b * 16 + t) * 256 + s) * 512 + coff;
    float4 o = *(float4*)ovp;
    float v0 = o.x * MEMDECAY + a0;
    float v1 = o.y * MEMDECAY + a1;
    float v2 = o.z * MEMDECAY + a2;
    float v3 = o.w * MEMDECAY + a3;
    float s0 = (v0 >= thr) ? 1.f : 0.f;
    float s1 = (v1 >= thr) ? 1.f : 0.f;
    float s2 = (v2 >= thr) ? 1.f : 0.f;
    float s3 = (v3 >= thr) ? 1.f : 0.f;
    float4 sp; sp.x = s0; sp.y = s1; sp.z = s2; sp.w = s3;
    *(float4*)outp = sp;
    float4 nv; nv.x = v0 * (1.f - s0); nv.y = v1 * (1.f - s1);
    nv.z = v2 * (1.f - s2); nv.w = v3 * (1.f - s3);
    *(float4*)ovp = nv;
    mycount += (int)(s0 + s1 + s2 + s3);
  }
  atomicAdd(&scnt, mycount);
  __syncthreads();
  if (tid == 0) atomicAdd(&cnt[16 + t], scnt);
}

// ---------------------------------------------------------------------------
extern "C" void kernel_launch(void* const* d_in, const int* in_sizes, int n_in,
                              void* d_out, int out_size, void* d_ws, size_t ws_size,
                              hipStream_t stream) {
  const float* x    = (const float*)d_in[0];
  const float* A    = (const float*)d_in[1];
  const float* C    = (const float*)d_in[2];
  const float* Wq   = (const float*)d_in[3];
  const float* bq   = (const float*)d_in[4];
  const float* Wkv  = (const float*)d_in[5];
  const float* bkv  = (const float*)d_in[6];
  const float* Wo   = (const float*)d_in[7];
  const float* bo   = (const float*)d_in[8];
  const float* th_s = (const float*)d_in[9];
  const float* th_o = (const float*)d_in[10];
  float* out = (float*)d_out;
  float* ws = (float*)d_ws;

  init_kernel<<<dim3(2181), dim3(256), 0, stream>>>(bq, C, Wkv, ws);
  kv_gemm_kernel<<<dim3(512), dim3(256), 0, stream>>>(x, ws + OFF_WT, bkv, ws);
  attp_kernel<<<dim3(512), dim3(256), 0, stream>>>(0, ws);
  for (int t = 0; t < TSTEPS; ++t) {
    combine_lifs_kernel<<<dim3(512), dim3(256), 0, stream>>>(t, A, Wq, bq, Wo, bo, th_s, ws);
    int g = (t < TSTEPS - 1) ? 768 : 256;
    fused_out_attp_kernel<<<dim3(g), dim3(256), 0, stream>>>(t, th_o, out, ws);
  }
}